// Round 1
// baseline (18060.480 us; speedup 1.0000x reference)
//
#include <hip/hip_runtime.h>
#include <math.h>

// Sizes
// T=10 B=512 N_ALL=23 N_AGENTS=22 NH=8 E=506 RNN_H=64 Z_DIM=92 IN_H=1592
// Node rows per group: 512*23 = 11776 ; edge rows per group: 512*506 = 259072
// gnn-out slice per group: 11776*8 = 94208 floats

__device__ __forceinline__ float elu_(float x){ return x>0.f ? x : __expf(x)-1.f; }
__device__ __forceinline__ float sp_(float x){ return fmaxf(x,0.f)+log1pf(__expf(-fabsf(x))); }
__device__ __forceinline__ float sig_(float x){ return 1.f/(1.f+__expf(-x)); }
__device__ __forceinline__ float wsum_(float v){
  #pragma unroll
  for (int o=32;o;o>>=1) v += __shfl_down(v,o,64);
  return v;
}

// ---- MLP1 on node features (nin=4): write pre-BN activations + stats ----
__global__ __launch_bounds__(256) void k_mlp_node4(
    const float* __restrict__ in, long gstride, float* __restrict__ out,
    const float* __restrict__ W1, const float* __restrict__ b1,
    const float* __restrict__ W2, const float* __restrict__ b2,
    float* __restrict__ stats)
{
  int g = blockIdx.y;
  int row = blockIdx.x*256 + threadIdx.x;            // [0, 11776)
  const float* inp = in + (size_t)g*gstride + (size_t)row*4;
  float x0=inp[0], x1=inp[1], x2=inp[2], x3=inp[3];
  float h1[8], h2[8];
  #pragma unroll
  for (int j=0;j<8;j++){
    float a = b1[j] + W1[j*4+0]*x0 + W1[j*4+1]*x1 + W1[j*4+2]*x2 + W1[j*4+3]*x3;
    h1[j] = elu_(a);
  }
  #pragma unroll
  for (int j=0;j<8;j++){
    float a = b2[j];
    #pragma unroll
    for (int k=0;k<8;k++) a += W2[j*8+k]*h1[k];
    h2[j] = elu_(a);
    out[((size_t)g*11776 + row)*8 + j] = h2[j];
  }
  #pragma unroll
  for (int j=0;j<8;j++){
    float s1v = wsum_(h2[j]);
    float s2v = wsum_(h2[j]*h2[j]);
    if ((threadIdx.x&63)==0){
      atomicAdd(&stats[g*16 + j], s1v);
      atomicAdd(&stats[g*16 + 8 + j], s2v);
    }
  }
}

// ---- apply BN (in place) on [G][11776][8] using raw sums ----
__global__ __launch_bounds__(256) void k_bn_apply(
    float* __restrict__ buf, const float* __restrict__ stats,
    const float* __restrict__ gam, const float* __restrict__ bet, float invN)
{
  int g = blockIdx.y;
  int e = blockIdx.x*256 + threadIdx.x;              // [0, 94208)
  int c = e & 7;
  float m = stats[g*16 + c]*invN;
  float v = stats[g*16 + 8 + c]*invN - m*m;
  float rs = rsqrtf(v + 1e-5f);
  float* p = buf + (size_t)g*94208 + e;
  *p = (*p - m)*rs*gam[c] + bet[c];
}

// ---- pass A: edge-MLP stats only (no materialization) ----
__global__ __launch_bounds__(256) void k_edge_stats(
    const float* __restrict__ xn, const float* __restrict__ W1, const float* __restrict__ b1,
    const float* __restrict__ W2, const float* __restrict__ b2, float* __restrict__ stats)
{
  int g = blockIdx.y;
  int row = blockIdx.x*256 + threadIdx.x;            // [0, 259072)
  int b = row / 506, e = row - b*506;
  int r = e / 22, jj = e - r*22;
  int s = jj + (jj>=r ? 1 : 0);
  const float* base = xn + (size_t)g*94208 + (size_t)b*184;
  const float* xs = base + s*8;
  const float* xr = base + r*8;
  float et0 = (jj==0 && r>=1 && r<=21) ? 1.f : 0.f;
  float et1 = (r==22) ? 1.f : 0.f;
  float h1[8], h2[8];
  #pragma unroll
  for (int j=0;j<8;j++){
    const float* w = W1 + j*18;
    float a = b1[j] + w[16]*et0 + w[17]*et1;
    #pragma unroll
    for (int k=0;k<8;k++) a += w[k]*xs[k];
    #pragma unroll
    for (int k=0;k<8;k++) a += w[8+k]*xr[k];
    h1[j] = elu_(a);
  }
  #pragma unroll
  for (int j=0;j<8;j++){
    float a = b2[j];
    #pragma unroll
    for (int k=0;k<8;k++) a += W2[j*8+k]*h1[k];
    h2[j] = elu_(a);
  }
  #pragma unroll
  for (int j=0;j<8;j++){
    float s1v = wsum_(h2[j]);
    float s2v = wsum_(h2[j]*h2[j]);
    if ((threadIdx.x&63)==0){
      atomicAdd(&stats[g*16+j], s1v);
      atomicAdd(&stats[g*16+8+j], s2v);
    }
  }
}

// ---- pass B: recompute edge MLP, BN-normalize, gather to receiver, MLP3 (+stats) ----
__global__ __launch_bounds__(256) void k_edge2node(
    const float* __restrict__ xn, const float* __restrict__ stats2,
    const float* __restrict__ g2, const float* __restrict__ bt2,
    const float* __restrict__ W1, const float* __restrict__ b1,
    const float* __restrict__ W2, const float* __restrict__ b2,
    const float* __restrict__ W3, const float* __restrict__ b3,
    const float* __restrict__ W4, const float* __restrict__ b4,
    float* __restrict__ out, float* __restrict__ stats3)
{
  int g = blockIdx.y;
  __shared__ float sc[8], sh[8];
  if (threadIdx.x < 8){
    int c = threadIdx.x;
    const float invN = 1.f/259072.f;
    float m = stats2[g*16+c]*invN;
    float v = stats2[g*16+8+c]*invN - m*m;
    float rs = rsqrtf(v+1e-5f);
    float s = rs*g2[c];
    sc[c] = s; sh[c] = bt2[c] - m*s;
  }
  __syncthreads();
  int row = blockIdx.x*256 + threadIdx.x;            // [0, 11776)
  int b = row/23, r = row - b*23;
  const float* base = xn + (size_t)g*94208 + (size_t)b*184;
  float xr[8];
  #pragma unroll
  for (int k=0;k<8;k++) xr[k] = base[r*8+k];
  float acc[8] = {0,0,0,0,0,0,0,0};
  float et0r = (r>=1 && r<=21) ? 1.f : 0.f;
  float et1 = (r==22) ? 1.f : 0.f;
  for (int jj=0;jj<22;jj++){
    int s = jj + (jj>=r ? 1 : 0);
    const float* xs = base + s*8;
    float et0 = (jj==0) ? et0r : 0.f;
    float h1[8];
    #pragma unroll
    for (int j=0;j<8;j++){
      const float* w = W1 + j*18;
      float a = b1[j] + w[16]*et0 + w[17]*et1;
      #pragma unroll
      for (int k=0;k<8;k++) a += w[k]*xs[k];
      #pragma unroll
      for (int k=0;k<8;k++) a += w[8+k]*xr[k];
      h1[j] = elu_(a);
    }
    #pragma unroll
    for (int j=0;j<8;j++){
      float a = b2[j];
      #pragma unroll
      for (int k=0;k<8;k++) a += W2[j*8+k]*h1[k];
      float h2 = elu_(a);
      acc[j] += h2*sc[j] + sh[j];
    }
  }
  const float inv23 = 1.f/23.f;
  float nt0 = (r<22)?inv23:0.f, nt1 = (r==22)?inv23:0.f;
  float h1b[8], o[8];
  #pragma unroll
  for (int j=0;j<8;j++){
    const float* w = W3 + j*10;
    float a = b3[j] + w[8]*nt0 + w[9]*nt1;
    #pragma unroll
    for (int k=0;k<8;k++) a += w[k]*(acc[k]*inv23);
    h1b[j] = elu_(a);
  }
  #pragma unroll
  for (int j=0;j<8;j++){
    float a = b4[j];
    #pragma unroll
    for (int k=0;k<8;k++) a += W4[j*8+k]*h1b[k];
    o[j] = elu_(a);
    out[((size_t)g*11776 + row)*8 + j] = o[j];
  }
  #pragma unroll
  for (int j=0;j<8;j++){
    float s1v = wsum_(o[j]);
    float s2v = wsum_(o[j]*o[j]);
    if ((threadIdx.x&63)==0){
      atomicAdd(&stats3[g*16+j], s1v);
      atomicAdd(&stats3[g*16+8+j], s2v);
    }
  }
}

// ---- heads: split-K tiled GEMM, C[head][512][92] += A(512x1592) * W(92x1592)^T ----
__global__ __launch_bounds__(256) void k_heads(
    const float* __restrict__ gy, const float* __restrict__ gx,
    const float* __restrict__ h,
    const float* __restrict__ Wpm, const float* __restrict__ bpm,
    const float* __restrict__ Wps, const float* __restrict__ bps,
    const float* __restrict__ Wem, const float* __restrict__ bem,
    const float* __restrict__ Wes, const float* __restrict__ bes,
    float* __restrict__ raw)
{
  int head = blockIdx.y;
  const float* W  = (head==0)?Wpm:(head==1)?Wps:(head==2)?Wem:Wes;
  const float* Bv = (head==0)?bpm:(head==1)?bps:(head==2)?bem:bes;
  const float* gsel = (head<2)?gy:gx;
  int b0 = blockIdx.x*64;
  int kbeg = blockIdx.z*199, kend = kbeg+199;
  __shared__ float As[16][68];
  __shared__ float Ws[16][100];
  int tid = threadIdx.x;
  int tb = tid & 15, tj = tid >> 4;
  float acc[4][6];
  #pragma unroll
  for (int u=0;u<4;u++){
    #pragma unroll
    for (int vv=0;vv<6;vv++) acc[u][vv]=0.f;
  }
  for (int k0=kbeg; k0<kend; k0+=16){
    #pragma unroll
    for (int l=0;l<4;l++){
      int lin = tid + 256*l;
      int kk = lin & 15, bl = lin >> 4;
      int i = k0 + kk;
      float v = 0.f;
      if (i < kend){
        int bb = b0 + bl;
        if (i < 184) v = gsel[bb*184 + i];
        else { int i2 = i - 184; v = h[(size_t)(i2>>6)*32768 + bb*64 + (i2&63)]; }
      }
      As[kk][bl] = v;
    }
    #pragma unroll
    for (int l=0;l<6;l++){
      int lin = tid + 256*l;
      int kk = lin & 15, jl = lin >> 4;
      int i = k0 + kk;
      float v = 0.f;
      if (i < kend && jl < 92) v = W[jl*1592 + i];
      Ws[kk][jl] = v;
    }
    __syncthreads();
    #pragma unroll
    for (int kk=0;kk<16;kk++){
      float4 a4 = *(const float4*)&As[kk][tb*4];
      float av[4] = {a4.x,a4.y,a4.z,a4.w};
      float wv[6];
      #pragma unroll
      for (int vv=0;vv<6;vv++) wv[vv] = Ws[kk][tj + 16*vv];
      #pragma unroll
      for (int u=0;u<4;u++){
        #pragma unroll
        for (int vv=0;vv<6;vv++) acc[u][vv] += av[u]*wv[vv];
      }
    }
    __syncthreads();
  }
  #pragma unroll
  for (int u=0;u<4;u++){
    int bb = b0 + tb*4 + u;
    #pragma unroll
    for (int vv=0;vv<6;vv++){
      int j = tj + 16*vv;
      if (j < 92){
        float val = acc[u][vv];
        if (blockIdx.z==0) val += Bv[j];
        atomicAdd(&raw[head*47104 + bb*92 + j], val);
      }
    }
  }
}

// ---- reparam sample + KLD ----
__global__ __launch_bounds__(256) void k_sample_kld(
    const float* __restrict__ raw, const float* __restrict__ eps_t,
    float* __restrict__ z, float* __restrict__ lkl)
{
  int i = blockIdx.x*256 + threadIdx.x;              // [0, 47104)
  float pm = raw[i];
  float ps = sp_(raw[47104 + i]);
  float em = raw[2*47104 + i];
  float es = sp_(raw[3*47104 + i]);
  z[i] = em + es*eps_t[i];
  float d = em - pm;
  float kl = 0.5f*(2.f*logf(ps/es) + (es*es + d*d)/(ps*ps) - 1.f);
  kl = wsum_(kl);
  if ((threadIdx.x&63)==0) atomicAdd(lkl, kl);
}

// ---- dec heads with BN fused inline ----
__global__ __launch_bounds__(256) void k_dec(
    const float* __restrict__ zg3, const float* __restrict__ stats3,
    const float* __restrict__ gam, const float* __restrict__ bet,
    const float* __restrict__ Wm, const float* __restrict__ Bm,
    const float* __restrict__ Wsd, const float* __restrict__ Bsd,
    float* __restrict__ odm, float* __restrict__ ods)
{
  __shared__ float sc[8], sh[8];
  if (threadIdx.x < 8){
    int c = threadIdx.x;
    const float invN = 1.f/11776.f;
    float m = stats3[c]*invN;
    float v = stats3[8+c]*invN - m*m;
    float rs = rsqrtf(v+1e-5f);
    sc[c] = rs*gam[c]; sh[c] = bet[c] - m*rs*gam[c];
  }
  __syncthreads();
  int idx = blockIdx.x*256 + threadIdx.x;            // [0, 90112)
  int hd = idx / 45056; int rem = idx - hd*45056;
  int b = rem / 88, j = rem - b*88;
  const float* W = hd ? Wsd : Wm;
  const float* a = zg3 + (size_t)b*184;
  float accv = hd ? Bsd[j] : Bm[j];
  for (int i=0;i<184;i++){
    float x = a[i]*sc[i&7] + sh[i&7];
    accv += W[j*184+i]*x;
  }
  if (hd) ods[(size_t)b*88+j] = sp_(accv);
  else    odm[(size_t)b*88+j] = accv;
}

// ---- per-agent GRU update ----
__global__ __launch_bounds__(256) void k_gru(
    const float* __restrict__ h_prev, const float* __restrict__ x_t,
    const float* __restrict__ z, const float* __restrict__ Wih,
    const float* __restrict__ Whh, const float* __restrict__ bih,
    const float* __restrict__ bhh, float* __restrict__ h_next)
{
  int a = blockIdx.x;                                 // agent
  __shared__ float Wh[12288];                         // [192][64]
  __shared__ float Wi[1728];                          // [192][9] padded
  __shared__ float hs[4][64];
  __shared__ float gins[4][8];
  int c = threadIdx.x, bl = threadIdx.y;
  int tid = bl*64 + c;
  const float* Wg = Whh + (size_t)a*12288;
  for (int i=tid;i<12288;i+=256) Wh[i] = Wg[i];
  const float* Wig = Wih + (size_t)a*1536;
  for (int i=tid;i<1536;i+=256) Wi[(i/8)*9 + (i&7)] = Wig[i];
  float bi0 = bih[a*192+c], bi1 = bih[a*192+64+c], bi2 = bih[a*192+128+c];
  float bh0 = bhh[a*192+c], bh1 = bhh[a*192+64+c], bh2 = bhh[a*192+128+c];
  for (int bc=0;bc<8;bc++){
    int b = blockIdx.y*32 + bc*4 + bl;
    __syncthreads();
    hs[bl][c] = h_prev[((size_t)a*512 + b)*64 + c];
    if (c < 8) gins[bl][c] = (c<4) ? x_t[b*92 + a*4 + c] : z[b*92 + a*4 + (c-4)];
    __syncthreads();
    float g0=bi0, g1=bi1, g2=bi2;
    #pragma unroll
    for (int k=0;k<8;k++){
      float xv = gins[bl][k];
      g0 += Wi[c*9+k]*xv;
      g1 += Wi[(64+c)*9+k]*xv;
      g2 += Wi[(128+c)*9+k]*xv;
    }
    float q0=bh0, q1=bh1, q2=bh2;
    for (int kk=0;kk<64;kk++){
      int k = (kk + c) & 63;
      float hv = hs[bl][k];
      q0 += Wh[c*64+k]*hv;
      q1 += Wh[(64+c)*64+k]*hv;
      q2 += Wh[(128+c)*64+k]*hv;
    }
    float rg = sig_(g0+q0);
    float zg = sig_(g1+q1);
    float ng = tanhf(g2 + rg*q2);
    h_next[((size_t)a*512 + b)*64 + c] = (1.f-zg)*ng + zg*hs[bl][c];
  }
}

__global__ void k_copy_lkl(const float* __restrict__ lkl, float* __restrict__ out){
  out[0] = lkl[0];
}

extern "C" void kernel_launch(void* const* d_in, const int* in_sizes, int n_in,
                              void* d_out, int out_size, void* d_ws, size_t ws_size,
                              hipStream_t stream)
{
  (void)in_sizes; (void)n_in; (void)out_size; (void)ws_size;
  const float* states=(const float*)d_in[0];
  const float* eps   =(const float*)d_in[1];
  const float *m1W1=(const float*)d_in[2],  *m1b1=(const float*)d_in[3],
              *m1W2=(const float*)d_in[4],  *m1b2=(const float*)d_in[5],
              *m1g =(const float*)d_in[6],  *m1bt=(const float*)d_in[7];
  const float *m2W1=(const float*)d_in[8],  *m2b1=(const float*)d_in[9],
              *m2W2=(const float*)d_in[10], *m2b2=(const float*)d_in[11],
              *m2g =(const float*)d_in[12], *m2bt=(const float*)d_in[13];
  const float *m3W1=(const float*)d_in[14], *m3b1=(const float*)d_in[15],
              *m3W2=(const float*)d_in[16], *m3b2=(const float*)d_in[17],
              *m3g =(const float*)d_in[18], *m3bt=(const float*)d_in[19];
  const float *emW=(const float*)d_in[20], *emB=(const float*)d_in[21];
  const float *esW=(const float*)d_in[22], *esB=(const float*)d_in[23];
  const float *pmW=(const float*)d_in[24], *pmB=(const float*)d_in[25];
  const float *psW=(const float*)d_in[26], *psB=(const float*)d_in[27];
  const float *dmW=(const float*)d_in[28], *dmB=(const float*)d_in[29];
  const float *dsW=(const float*)d_in[30], *dsB=(const float*)d_in[31];
  const float *gWih=(const float*)d_in[32], *gWhh=(const float*)d_in[33];
  const float *gbih=(const float*)d_in[34], *gbhh=(const float*)d_in[35];
  float* out = (float*)d_out;
  float* ws  = (float*)d_ws;

  // workspace layout (floats); total 5,635,057 floats = 22.5 MB
  float* xn  = ws;                 // [2][10][11776][8]  = 1,884,160
  float* g3  = ws + 1884160;       // [2][10][11776][8]  = 1,884,160
  float* zxn = ws + 3768320;       // [11776][8]         = 94,208
  float* zg3 = ws + 3862528;       // [11776][8]         = 94,208
  float* zb  = ws + 3956736;       // [512][92]          = 47,104
  float* h0  = ws + 4003840;       // [22][512][64]      = 720,896
  float* h1  = ws + 4724736;       // [22][512][64]      = 720,896
  float* raw = ws + 5445632;       // [4][512][92]       = 188,416
  float* zs1 = ws + 5634048;       // 16  (z-gnn stats, contiguous after raw)
  float* zs2 = zs1 + 16;           // 16
  float* zs3 = zs1 + 32;           // 16
  float* s1  = ws + 5634096;       // [2][10][16] = 320
  float* s2  = s1 + 320;           // 320
  float* s3  = s1 + 640;           // 320
  float* lkl = ws + 5635056;       // 1

  hipMemsetAsync(s1, 0, 961*sizeof(float), stream);      // s1,s2,s3,lkl
  hipMemsetAsync(h0, 0, 720896*sizeof(float), stream);

  // ---- precompute gnn(y_t, p=0) and gnn(x_{t+1}, p=1), all t in parallel ----
  for (int p=0;p<2;p++){
    k_mlp_node4<<<dim3(46,10),256,0,stream>>>(states + p*47104, 47104L,
        xn + (size_t)p*942080, m1W1+p*32, m1b1+p*8, m1W2+p*64, m1b2+p*8, s1+p*160);
    k_bn_apply<<<dim3(368,10),256,0,stream>>>(xn + (size_t)p*942080, s1+p*160,
        m1g+p*8, m1bt+p*8, 1.f/11776.f);
    k_edge_stats<<<dim3(1012,10),256,0,stream>>>(xn + (size_t)p*942080,
        m2W1+p*144, m2b1+p*8, m2W2+p*64, m2b2+p*8, s2+p*160);
    k_edge2node<<<dim3(46,10),256,0,stream>>>(xn + (size_t)p*942080, s2+p*160,
        m2g+p*8, m2bt+p*8, m2W1+p*144, m2b1+p*8, m2W2+p*64, m2b2+p*8,
        m3W1+p*80, m3b1+p*8, m3W2+p*64, m3b2+p*8,
        g3 + (size_t)p*942080, s3+p*160);
    k_bn_apply<<<dim3(368,10),256,0,stream>>>(g3 + (size_t)p*942080, s3+p*160,
        m3g+p*8, m3bt+p*8, 1.f/11776.f);
  }

  // ---- sequential scan over t ----
  float* hp = h0; float* hn = h1;
  for (int t=0;t<10;t++){
    hipMemsetAsync(raw, 0, (188416+48)*sizeof(float), stream);  // raw + z-stats
    k_heads<<<dim3(8,4,8),256,0,stream>>>(g3 + (size_t)t*94208,
        g3 + 942080 + (size_t)t*94208, hp,
        pmW,pmB, psW,psB, emW,emB, esW,esB, raw);
    k_sample_kld<<<dim3(184),256,0,stream>>>(raw, eps + (size_t)t*47104, zb, lkl);
    // z-gnn (param set 2)
    k_mlp_node4<<<dim3(46,1),256,0,stream>>>(zb, 0L, zxn,
        m1W1+64, m1b1+16, m1W2+128, m1b2+16, zs1);
    k_bn_apply<<<dim3(368,1),256,0,stream>>>(zxn, zs1, m1g+16, m1bt+16, 1.f/11776.f);
    k_edge_stats<<<dim3(1012,1),256,0,stream>>>(zxn, m2W1+288, m2b1+16, m2W2+128, m2b2+16, zs2);
    k_edge2node<<<dim3(46,1),256,0,stream>>>(zxn, zs2, m2g+16, m2bt+16,
        m2W1+288, m2b1+16, m2W2+128, m2b2+16,
        m3W1+160, m3b1+16, m3W2+128, m3b2+16, zg3, zs3);
    k_dec<<<dim3(352),256,0,stream>>>(zg3, zs3, m3g+16, m3bt+16,
        dmW,dmB, dsW,dsB, out + (size_t)t*45056, out + 450560 + (size_t)t*45056);
    k_gru<<<dim3(22,16),dim3(64,4),0,stream>>>(hp, states + (size_t)(t+1)*47104, zb,
        gWih, gWhh, gbih, gbhh, hn);
    float* tmp = hp; hp = hn; hn = tmp;
  }
  k_copy_lkl<<<1,1,0,stream>>>(lkl, out + 901120);
}

// Round 2
// 2210.377 us; speedup vs baseline: 8.1708x; 8.1708x over previous
//
#include <hip/hip_runtime.h>
#include <math.h>

// T=10 B=512 N_ALL=23 N_AGENTS=22 NH=8 E=506 RNN_H=64 Z_DIM=92 IN_H=1592
// node rows/group: 11776 ; edge rows/group: 259072 ; gnn slice: 94208 floats

__device__ __forceinline__ float elu_(float x){ return x>0.f ? x : __expf(x)-1.f; }
__device__ __forceinline__ float sp_(float x){ return fmaxf(x,0.f)+log1pf(__expf(-fabsf(x))); }
__device__ __forceinline__ float sig_(float x){ return 1.f/(1.f+__expf(-x)); }
__device__ __forceinline__ float wsum_(float v){
  #pragma unroll
  for (int o=32;o;o>>=1) v += __shfl_down(v,o,64);
  return v;
}

// block-cooperative: reduce n x 16 partial sums -> BN scale/shift in LDS
__device__ __forceinline__ void reduce_bn_(const float* __restrict__ part, int n,
    float invN, const float* __restrict__ gam, const float* __restrict__ bet,
    float* sc, float* sh, float* tmp)
{
  int tid = threadIdx.x;
  int c = tid & 15, i0 = tid >> 4;
  float s = 0.f;
  for (int i = i0; i < n; i += 16) s += part[i*16 + c];
  tmp[i0*16 + c] = s;
  __syncthreads();
  if (tid < 16){
    float v = 0.f;
    #pragma unroll
    for (int i=0;i<16;i++) v += tmp[i*16 + tid];
    tmp[tid] = v;
  }
  __syncthreads();
  if (tid < 8){
    float m = tmp[tid]*invN;
    float var = tmp[8+tid]*invN - m*m;
    float rs = rsqrtf(var + 1e-5f);
    float s2 = rs*gam[tid];
    sc[tid] = s2; sh[tid] = bet[tid] - m*s2;
  }
  __syncthreads();
}

// block stats: h[8] per thread -> part[blk*16 + {sum8, sumsq8}]
__device__ __forceinline__ void block_stats_(const float h[8], float* __restrict__ part,
                                             float red[4][16])
{
  int wid = threadIdx.x >> 6, lane = threadIdx.x & 63;
  #pragma unroll
  for (int j=0;j<8;j++){
    float a = wsum_(h[j]);
    float b = wsum_(h[j]*h[j]);
    if (lane==0){ red[wid][j]=a; red[wid][8+j]=b; }
  }
  __syncthreads();
  if (threadIdx.x < 16)
    part[threadIdx.x] = red[0][threadIdx.x]+red[1][threadIdx.x]
                       +red[2][threadIdx.x]+red[3][threadIdx.x];
}

// ---- MLP1 on node features (nin=4): pre-BN activations + per-block stats ----
__global__ __launch_bounds__(256) void k_mlp_node4(
    const float* __restrict__ in, long gstride, float* __restrict__ out,
    const float* __restrict__ W1, const float* __restrict__ b1,
    const float* __restrict__ W2, const float* __restrict__ b2,
    float* __restrict__ part)
{
  int g = blockIdx.y;
  int row = blockIdx.x*256 + threadIdx.x;            // [0, 11776)
  const float* inp = in + (size_t)g*gstride + (size_t)row*4;
  float x0=inp[0], x1=inp[1], x2=inp[2], x3=inp[3];
  float h1[8], h2[8];
  #pragma unroll
  for (int j=0;j<8;j++){
    float a = b1[j] + W1[j*4+0]*x0 + W1[j*4+1]*x1 + W1[j*4+2]*x2 + W1[j*4+3]*x3;
    h1[j] = elu_(a);
  }
  #pragma unroll
  for (int j=0;j<8;j++){
    float a = b2[j];
    #pragma unroll
    for (int k=0;k<8;k++) a += W2[j*8+k]*h1[k];
    h2[j] = elu_(a);
    out[((size_t)g*11776 + row)*8 + j] = h2[j];
  }
  __shared__ float red[4][16];
  block_stats_(h2, part + ((size_t)g*46 + blockIdx.x)*16, red);
}

// ---- edge-MLP stats (BN-1 fused inline via partial reduce) ----
__global__ __launch_bounds__(256) void k_edge_stats(
    const float* __restrict__ xn, const float* __restrict__ p1,
    const float* __restrict__ g1, const float* __restrict__ bt1,
    const float* __restrict__ W1, const float* __restrict__ b1,
    const float* __restrict__ W2, const float* __restrict__ b2,
    float* __restrict__ p2)
{
  int g = blockIdx.y;
  __shared__ float tmp[256], sc1[8], sh1[8];
  reduce_bn_(p1 + (size_t)g*736, 46, 1.f/11776.f, g1, bt1, sc1, sh1, tmp);
  int row = blockIdx.x*256 + threadIdx.x;            // [0, 259072)
  int b = row / 506, e = row - b*506;
  int r = e / 22, jj = e - r*22;
  int s = jj + (jj>=r ? 1 : 0);
  const float* base = xn + (size_t)g*94208 + (size_t)b*184;
  float xs[8], xr[8];
  #pragma unroll
  for (int k=0;k<8;k++){ xs[k] = base[s*8+k]*sc1[k]+sh1[k]; xr[k] = base[r*8+k]*sc1[k]+sh1[k]; }
  float et0 = (jj==0 && r>=1 && r<=21) ? 1.f : 0.f;
  float et1 = (r==22) ? 1.f : 0.f;
  float h1[8], h2[8];
  #pragma unroll
  for (int j=0;j<8;j++){
    const float* w = W1 + j*18;
    float a = b1[j] + w[16]*et0 + w[17]*et1;
    #pragma unroll
    for (int k=0;k<8;k++) a += w[k]*xs[k];
    #pragma unroll
    for (int k=0;k<8;k++) a += w[8+k]*xr[k];
    h1[j] = elu_(a);
  }
  #pragma unroll
  for (int j=0;j<8;j++){
    float a = b2[j];
    #pragma unroll
    for (int k=0;k<8;k++) a += W2[j*8+k]*h1[k];
    h2[j] = elu_(a);
  }
  __shared__ float red[4][16];
  block_stats_(h2, p2 + ((size_t)g*1012 + blockIdx.x)*16, red);
}

// ---- recompute edge MLP (BN-1 + BN-2 inline), edge2node gather, MLP3 + stats ----
__global__ __launch_bounds__(256) void k_edge2node(
    const float* __restrict__ xn, const float* __restrict__ p1,
    const float* __restrict__ g1, const float* __restrict__ bt1,
    const float* __restrict__ p2, const float* __restrict__ g2,
    const float* __restrict__ bt2,
    const float* __restrict__ W1, const float* __restrict__ b1,
    const float* __restrict__ W2, const float* __restrict__ b2,
    const float* __restrict__ W3, const float* __restrict__ b3,
    const float* __restrict__ W4, const float* __restrict__ b4,
    float* __restrict__ out, float* __restrict__ p3)
{
  int g = blockIdx.y;
  __shared__ float tmp[256], sc1[8], sh1[8], sc2[8], sh2[8];
  reduce_bn_(p1 + (size_t)g*736,   46,   1.f/11776.f,  g1, bt1, sc1, sh1, tmp);
  reduce_bn_(p2 + (size_t)g*16192, 1012, 1.f/259072.f, g2, bt2, sc2, sh2, tmp);
  int row = blockIdx.x*256 + threadIdx.x;            // [0, 11776)
  int b = row/23, r = row - b*23;
  const float* base = xn + (size_t)g*94208 + (size_t)b*184;
  float xr[8];
  #pragma unroll
  for (int k=0;k<8;k++) xr[k] = base[r*8+k]*sc1[k]+sh1[k];
  float acc[8] = {0,0,0,0,0,0,0,0};
  float et0r = (r>=1 && r<=21) ? 1.f : 0.f;
  float et1 = (r==22) ? 1.f : 0.f;
  for (int jj=0;jj<22;jj++){
    int s = jj + (jj>=r ? 1 : 0);
    const float* xsp = base + s*8;
    float et0 = (jj==0) ? et0r : 0.f;
    float h1[8];
    #pragma unroll
    for (int j=0;j<8;j++){
      const float* w = W1 + j*18;
      float a = b1[j] + w[16]*et0 + w[17]*et1;
      #pragma unroll
      for (int k=0;k<8;k++) a += w[k]*(xsp[k]*sc1[k]+sh1[k]);
      #pragma unroll
      for (int k=0;k<8;k++) a += w[8+k]*xr[k];
      h1[j] = elu_(a);
    }
    #pragma unroll
    for (int j=0;j<8;j++){
      float a = b2[j];
      #pragma unroll
      for (int k=0;k<8;k++) a += W2[j*8+k]*h1[k];
      float h2 = elu_(a);
      acc[j] += h2*sc2[j] + sh2[j];
    }
  }
  const float inv23 = 1.f/23.f;
  float nt0 = (r<22)?inv23:0.f, nt1 = (r==22)?inv23:0.f;
  float h1b[8], o[8];
  #pragma unroll
  for (int j=0;j<8;j++){
    const float* w = W3 + j*10;
    float a = b3[j] + w[8]*nt0 + w[9]*nt1;
    #pragma unroll
    for (int k=0;k<8;k++) a += w[k]*(acc[k]*inv23);
    h1b[j] = elu_(a);
  }
  #pragma unroll
  for (int j=0;j<8;j++){
    float a = b4[j];
    #pragma unroll
    for (int k=0;k<8;k++) a += W4[j*8+k]*h1b[k];
    o[j] = elu_(a);
    out[((size_t)g*11776 + row)*8 + j] = o[j];
  }
  __shared__ float red[4][16];
  block_stats_(o, p3 + ((size_t)g*46 + blockIdx.x)*16, red);
}

// ---- apply BN-3 (precompute g3 only), stats reduced inline ----
__global__ __launch_bounds__(256) void k_bn_apply3(
    float* __restrict__ buf, const float* __restrict__ p3,
    const float* __restrict__ gam, const float* __restrict__ bet)
{
  int g = blockIdx.y;
  __shared__ float tmp[256], sc[8], sh[8];
  reduce_bn_(p3 + (size_t)g*736, 46, 1.f/11776.f, gam, bet, sc, sh, tmp);
  int e = blockIdx.x*256 + threadIdx.x;              // [0, 94208)
  float* p = buf + (size_t)g*94208 + e;
  *p = (*p)*sc[e&7] + sh[e&7];
}

// ---- heads: split-K tiled GEMM -> partials rawp[8][4][512][92] ----
__global__ __launch_bounds__(256) void k_heads(
    const float* __restrict__ gy, const float* __restrict__ gx,
    const float* __restrict__ h,
    const float* __restrict__ Wpm, const float* __restrict__ Wps,
    const float* __restrict__ Wem, const float* __restrict__ Wes,
    float* __restrict__ rawp)
{
  int head = blockIdx.y;
  const float* W  = (head==0)?Wpm:(head==1)?Wps:(head==2)?Wem:Wes;
  const float* gsel = (head<2)?gy:gx;
  int b0 = blockIdx.x*64;
  int kbeg = blockIdx.z*199, kend = kbeg+199;
  __shared__ float As[16][68];
  __shared__ float Ws[16][100];
  int tid = threadIdx.x;
  int tb = tid & 15, tj = tid >> 4;
  float acc[4][6];
  #pragma unroll
  for (int u=0;u<4;u++)
    #pragma unroll
    for (int vv=0;vv<6;vv++) acc[u][vv]=0.f;
  for (int k0=kbeg; k0<kend; k0+=16){
    #pragma unroll
    for (int l=0;l<4;l++){
      int lin = tid + 256*l;
      int kk = lin & 15, bl = lin >> 4;
      int i = k0 + kk;
      float v = 0.f;
      if (i < kend){
        int bb = b0 + bl;
        if (i < 184) v = gsel[bb*184 + i];
        else { int i2 = i - 184; v = h[(size_t)(i2>>6)*32768 + bb*64 + (i2&63)]; }
      }
      As[kk][bl] = v;
    }
    #pragma unroll
    for (int l=0;l<6;l++){
      int lin = tid + 256*l;
      int kk = lin & 15, jl = lin >> 4;
      int i = k0 + kk;
      float v = 0.f;
      if (i < kend && jl < 92) v = W[jl*1592 + i];
      Ws[kk][jl] = v;
    }
    __syncthreads();
    #pragma unroll
    for (int kk=0;kk<16;kk++){
      float4 a4 = *(const float4*)&As[kk][tb*4];
      float av[4] = {a4.x,a4.y,a4.z,a4.w};
      float wv[6];
      #pragma unroll
      for (int vv=0;vv<6;vv++) wv[vv] = Ws[kk][tj + 16*vv];
      #pragma unroll
      for (int u=0;u<4;u++)
        #pragma unroll
        for (int vv=0;vv<6;vv++) acc[u][vv] += av[u]*wv[vv];
    }
    __syncthreads();
  }
  float* dst = rawp + (size_t)blockIdx.z*188416 + (size_t)head*47104;
  #pragma unroll
  for (int u=0;u<4;u++){
    int bb = b0 + tb*4 + u;
    #pragma unroll
    for (int vv=0;vv<6;vv++){
      int j = tj + 16*vv;
      if (j < 92) dst[bb*92 + j] = acc[u][vv];
    }
  }
}

// ---- combine split-K + bias, reparam sample, KLD partial per block ----
__global__ __launch_bounds__(256) void k_sample_kld(
    const float* __restrict__ rawp,
    const float* __restrict__ bpm, const float* __restrict__ bps,
    const float* __restrict__ bem, const float* __restrict__ bes,
    const float* __restrict__ eps_t, float* __restrict__ z,
    float* __restrict__ lklp)
{
  int i = blockIdx.x*256 + threadIdx.x;              // [0, 47104)
  int j = i - (i/92)*92;
  float pm=bpm[j], ps=bps[j], em=bem[j], es=bes[j];
  #pragma unroll
  for (int zz=0; zz<8; zz++){
    const float* r = rawp + (size_t)zz*188416 + i;
    pm += r[0]; ps += r[47104]; em += r[2*47104]; es += r[3*47104];
  }
  ps = sp_(ps); es = sp_(es);
  z[i] = em + es*eps_t[i];
  float d = em - pm;
  float kl = 0.5f*(2.f*logf(ps/es) + (es*es + d*d)/(ps*ps) - 1.f);
  __shared__ float red[4];
  kl = wsum_(kl);
  if ((threadIdx.x&63)==0) red[threadIdx.x>>6] = kl;
  __syncthreads();
  if (threadIdx.x==0) lklp[blockIdx.x] = red[0]+red[1]+red[2]+red[3];
}

// ---- dec heads, BN-3 fused inline (stats reduced in-block) ----
__global__ __launch_bounds__(256) void k_dec(
    const float* __restrict__ zg3, const float* __restrict__ p3,
    const float* __restrict__ gam, const float* __restrict__ bet,
    const float* __restrict__ Wm, const float* __restrict__ Bm,
    const float* __restrict__ Wsd, const float* __restrict__ Bsd,
    float* __restrict__ odm, float* __restrict__ ods)
{
  __shared__ float tmp[256], sc[8], sh[8];
  reduce_bn_(p3, 46, 1.f/11776.f, gam, bet, sc, sh, tmp);
  int idx = blockIdx.x*256 + threadIdx.x;            // [0, 90112)
  int hd = idx / 45056; int rem = idx - hd*45056;
  int b = rem / 88, j = rem - b*88;
  const float* W = hd ? Wsd : Wm;
  const float* a = zg3 + (size_t)b*184;
  float accv = hd ? Bsd[j] : Bm[j];
  for (int i=0;i<184;i++){
    float x = a[i]*sc[i&7] + sh[i&7];
    accv += W[j*184+i]*x;
  }
  if (hd) ods[(size_t)b*88+j] = sp_(accv);
  else    odm[(size_t)b*88+j] = accv;
}

// ---- per-agent GRU update ----
__global__ __launch_bounds__(256) void k_gru(
    const float* __restrict__ h_prev, const float* __restrict__ x_t,
    const float* __restrict__ z, const float* __restrict__ Wih,
    const float* __restrict__ Whh, const float* __restrict__ bih,
    const float* __restrict__ bhh, float* __restrict__ h_next)
{
  int a = blockIdx.x;
  __shared__ float Wh[12288];
  __shared__ float Wi[1728];
  __shared__ float hs[4][64];
  __shared__ float gins[4][8];
  int c = threadIdx.x, bl = threadIdx.y;
  int tid = bl*64 + c;
  const float* Wg = Whh + (size_t)a*12288;
  for (int i=tid;i<12288;i+=256) Wh[i] = Wg[i];
  const float* Wig = Wih + (size_t)a*1536;
  for (int i=tid;i<1536;i+=256) Wi[(i/8)*9 + (i&7)] = Wig[i];
  float bi0 = bih[a*192+c], bi1 = bih[a*192+64+c], bi2 = bih[a*192+128+c];
  float bh0 = bhh[a*192+c], bh1 = bhh[a*192+64+c], bh2 = bhh[a*192+128+c];
  for (int bc=0;bc<8;bc++){
    int b = blockIdx.y*32 + bc*4 + bl;
    __syncthreads();
    hs[bl][c] = h_prev[((size_t)a*512 + b)*64 + c];
    if (c < 8) gins[bl][c] = (c<4) ? x_t[b*92 + a*4 + c] : z[b*92 + a*4 + (c-4)];
    __syncthreads();
    float g0=bi0, g1=bi1, g2=bi2;
    #pragma unroll
    for (int k=0;k<8;k++){
      float xv = gins[bl][k];
      g0 += Wi[c*9+k]*xv;
      g1 += Wi[(64+c)*9+k]*xv;
      g2 += Wi[(128+c)*9+k]*xv;
    }
    float q0=bh0, q1=bh1, q2=bh2;
    for (int kk=0;kk<64;kk++){
      int k = (kk + c) & 63;
      float hv = hs[bl][k];
      q0 += Wh[c*64+k]*hv;
      q1 += Wh[(64+c)*64+k]*hv;
      q2 += Wh[(128+c)*64+k]*hv;
    }
    float rg = sig_(g0+q0);
    float zg = sig_(g1+q1);
    float ng = tanhf(g2 + rg*q2);
    h_next[((size_t)a*512 + b)*64 + c] = (1.f-zg)*ng + zg*hs[bl][c];
  }
}

__global__ __launch_bounds__(256) void k_final(const float* __restrict__ lklp,
                                               float* __restrict__ out){
  __shared__ float red[4];
  float s = 0.f;
  for (int i = threadIdx.x; i < 1840; i += 256) s += lklp[i];
  s = wsum_(s);
  if ((threadIdx.x&63)==0) red[threadIdx.x>>6]=s;
  __syncthreads();
  if (threadIdx.x==0) out[0] = red[0]+red[1]+red[2]+red[3];
}

extern "C" void kernel_launch(void* const* d_in, const int* in_sizes, int n_in,
                              void* d_out, int out_size, void* d_ws, size_t ws_size,
                              hipStream_t stream)
{
  (void)in_sizes; (void)n_in; (void)out_size; (void)ws_size;
  const float* states=(const float*)d_in[0];
  const float* eps   =(const float*)d_in[1];
  const float *m1W1=(const float*)d_in[2],  *m1b1=(const float*)d_in[3],
              *m1W2=(const float*)d_in[4],  *m1b2=(const float*)d_in[5],
              *m1g =(const float*)d_in[6],  *m1bt=(const float*)d_in[7];
  const float *m2W1=(const float*)d_in[8],  *m2b1=(const float*)d_in[9],
              *m2W2=(const float*)d_in[10], *m2b2=(const float*)d_in[11],
              *m2g =(const float*)d_in[12], *m2bt=(const float*)d_in[13];
  const float *m3W1=(const float*)d_in[14], *m3b1=(const float*)d_in[15],
              *m3W2=(const float*)d_in[16], *m3b2=(const float*)d_in[17],
              *m3g =(const float*)d_in[18], *m3bt=(const float*)d_in[19];
  const float *emW=(const float*)d_in[20], *emB=(const float*)d_in[21];
  const float *esW=(const float*)d_in[22], *esB=(const float*)d_in[23];
  const float *pmW=(const float*)d_in[24], *pmB=(const float*)d_in[25];
  const float *psW=(const float*)d_in[26], *psB=(const float*)d_in[27];
  const float *dmW=(const float*)d_in[28], *dmB=(const float*)d_in[29];
  const float *dsW=(const float*)d_in[30], *dsB=(const float*)d_in[31];
  const float *gWih=(const float*)d_in[32], *gWhh=(const float*)d_in[33];
  const float *gbih=(const float*)d_in[34], *gbhh=(const float*)d_in[35];
  float* out = (float*)d_out;
  float* ws  = (float*)d_ws;

  // persistent region
  float* g3   = ws;                   // [2][10][11776][8] = 1,884,160
  float* h0   = ws + 1884160;         // 720,896
  float* h1   = ws + 2605056;         // 720,896
  float* zb   = ws + 3325952;         // 47,104
  float* lklp = ws + 3373056;         // 1,840
  float* scr  = ws + 3374896;         // scratch, precompute/loop overlap
  // precompute view of scratch
  float* xn   = scr;                  // [2][10][11776][8] = 1,884,160
  float* p1p  = scr + 1884160;        // [20][46][16]  = 14,720
  float* p2p  = scr + 1898880;        // [20][1012][16]= 323,840
  float* p3p  = scr + 2222720;        // [20][46][16]  = 14,720
  // loop view of scratch (precompute fully drained first; stream-ordered)
  float* rawp = scr;                  // [8][4][512][92] = 1,507,328
  float* zxn  = scr + 1507328;        // 94,208
  float* zg3  = scr + 1601536;        // 94,208
  float* zp1  = scr + 1695744;        // 736
  float* zp2  = scr + 1696480;        // 16,192
  float* zp3  = scr + 1712672;        // 736

  hipMemsetAsync(h0, 0, 720896*sizeof(float), stream);

  // ---- precompute gnn(y,p=0) and gnn(x,p=1) for all t ----
  for (int p=0;p<2;p++){
    k_mlp_node4<<<dim3(46,10),256,0,stream>>>(states + p*47104, 47104L,
        xn + (size_t)p*942080, m1W1+p*32, m1b1+p*8, m1W2+p*64, m1b2+p*8,
        p1p + (size_t)p*7360);
    k_edge_stats<<<dim3(1012,10),256,0,stream>>>(xn + (size_t)p*942080,
        p1p + (size_t)p*7360, m1g+p*8, m1bt+p*8,
        m2W1+p*144, m2b1+p*8, m2W2+p*64, m2b2+p*8, p2p + (size_t)p*161920);
    k_edge2node<<<dim3(46,10),256,0,stream>>>(xn + (size_t)p*942080,
        p1p + (size_t)p*7360, m1g+p*8, m1bt+p*8,
        p2p + (size_t)p*161920, m2g+p*8, m2bt+p*8,
        m2W1+p*144, m2b1+p*8, m2W2+p*64, m2b2+p*8,
        m3W1+p*80, m3b1+p*8, m3W2+p*64, m3b2+p*8,
        g3 + (size_t)p*942080, p3p + (size_t)p*7360);
    k_bn_apply3<<<dim3(368,10),256,0,stream>>>(g3 + (size_t)p*942080,
        p3p + (size_t)p*7360, m3g+p*8, m3bt+p*8);
  }

  // ---- sequential scan ----
  float* hp = h0; float* hn = h1;
  for (int t=0;t<10;t++){
    k_heads<<<dim3(8,4,8),256,0,stream>>>(g3 + (size_t)t*94208,
        g3 + 942080 + (size_t)t*94208, hp, pmW, psW, emW, esW, rawp);
    k_sample_kld<<<dim3(184),256,0,stream>>>(rawp, pmB, psB, emB, esB,
        eps + (size_t)t*47104, zb, lklp + t*184);
    k_mlp_node4<<<dim3(46,1),256,0,stream>>>(zb, 0L, zxn,
        m1W1+64, m1b1+16, m1W2+128, m1b2+16, zp1);
    k_edge_stats<<<dim3(1012,1),256,0,stream>>>(zxn, zp1, m1g+16, m1bt+16,
        m2W1+288, m2b1+16, m2W2+128, m2b2+16, zp2);
    k_edge2node<<<dim3(46,1),256,0,stream>>>(zxn, zp1, m1g+16, m1bt+16,
        zp2, m2g+16, m2bt+16,
        m2W1+288, m2b1+16, m2W2+128, m2b2+16,
        m3W1+160, m3b1+16, m3W2+128, m3b2+16, zg3, zp3);
    k_dec<<<dim3(352),256,0,stream>>>(zg3, zp3, m3g+16, m3bt+16,
        dmW, dmB, dsW, dsB, out + (size_t)t*45056, out + 450560 + (size_t)t*45056);
    k_gru<<<dim3(22,16),dim3(64,4),0,stream>>>(hp, states + (size_t)(t+1)*47104, zb,
        gWih, gWhh, gbih, gbhh, hn);
    float* tmpp = hp; hp = hn; hn = tmpp;
  }
  k_final<<<1,256,0,stream>>>(lklp, out + 901120);
}

// Round 3
// 1986.291 us; speedup vs baseline: 9.0926x; 1.1128x over previous
//
#include <hip/hip_runtime.h>
#include <math.h>

// T=10 B=512 N_ALL=23 N_AGENTS=22 NH=8 E=506 RNN_H=64 Z_DIM=92 IN_H=1592
// node rows/group: 11776 ; edge rows/group: 259072 ; gnn slice: 94208 floats

__device__ __forceinline__ float elu_(float x){ return x>0.f ? x : __expf(x)-1.f; }
__device__ __forceinline__ float sp_(float x){ return fmaxf(x,0.f)+log1pf(__expf(-fabsf(x))); }
__device__ __forceinline__ float sig_(float x){ return 1.f/(1.f+__expf(-x)); }
__device__ __forceinline__ float wsum_(float v){
  #pragma unroll
  for (int o=32;o;o>>=1) v += __shfl_down(v,o,64);
  return v;
}

// block-cooperative (256 thr): reduce n x 16 partials -> BN scale/shift in LDS
__device__ __forceinline__ void reduce_bn_(const float* __restrict__ part, int n,
    float invN, const float* __restrict__ gam, const float* __restrict__ bet,
    float* sc, float* sh, float* tmp)
{
  int tid = threadIdx.x;
  int c = tid & 15, i0 = tid >> 4;
  float s = 0.f;
  for (int i = i0; i < n; i += 16) s += part[i*16 + c];
  tmp[i0*16 + c] = s;
  __syncthreads();
  if (tid < 16){
    float v = 0.f;
    #pragma unroll
    for (int i=0;i<16;i++) v += tmp[i*16 + tid];
    tmp[tid] = v;
  }
  __syncthreads();
  if (tid < 8){
    float m = tmp[tid]*invN;
    float var = tmp[8+tid]*invN - m*m;
    float rs = rsqrtf(var + 1e-5f);
    float s2 = rs*gam[tid];
    sc[tid] = s2; sh[tid] = bet[tid] - m*s2;
  }
  __syncthreads();
}

// block stats (256 thr): h[8]/thread -> part[16] = {sum8, sumsq8}
__device__ __forceinline__ void block_stats_(const float h[8], float* __restrict__ part,
                                             float red[4][16])
{
  int wid = threadIdx.x >> 6, lane = threadIdx.x & 63;
  #pragma unroll
  for (int j=0;j<8;j++){
    float a = wsum_(h[j]);
    float b = wsum_(h[j]*h[j]);
    if (lane==0){ red[wid][j]=a; red[wid][8+j]=b; }
  }
  __syncthreads();
  if (threadIdx.x < 16)
    part[threadIdx.x] = red[0][threadIdx.x]+red[1][threadIdx.x]
                       +red[2][threadIdx.x]+red[3][threadIdx.x];
}

// ---- precompute MLP1: g in [0,20), p=g/10, t=g%10; input slice (t+p) ----
__global__ __launch_bounds__(256) void k_pre_mlp1(
    const float* __restrict__ states, float* __restrict__ out,
    const float* __restrict__ W1b, const float* __restrict__ b1b,
    const float* __restrict__ W2b, const float* __restrict__ b2b,
    float* __restrict__ part)
{
  int g = blockIdx.y; int p = g/10; int t = g - p*10;
  const float* W1 = W1b + p*32; const float* b1 = b1b + p*8;
  const float* W2 = W2b + p*64; const float* b2 = b2b + p*8;
  int row = blockIdx.x*256 + threadIdx.x;            // [0, 11776)
  float4 x4 = *(const float4*)(states + (size_t)(t+p)*47104 + 4*(size_t)row);
  float h1[8], h2[8];
  #pragma unroll
  for (int j=0;j<8;j++){
    float a = b1[j] + W1[j*4+0]*x4.x + W1[j*4+1]*x4.y + W1[j*4+2]*x4.z + W1[j*4+3]*x4.w;
    h1[j] = elu_(a);
  }
  #pragma unroll
  for (int j=0;j<8;j++){
    float a = b2[j];
    #pragma unroll
    for (int k=0;k<8;k++) a += W2[j*8+k]*h1[k];
    h2[j] = elu_(a);
    out[((size_t)g*11776 + row)*8 + j] = h2[j];
  }
  __shared__ float red[4][16];
  block_stats_(h2, part + ((size_t)g*46 + blockIdx.x)*16, red);
}

// ---- edge MLP stats pass (BN1 inline via 46-partial reduce) ----
__global__ __launch_bounds__(256) void k_edge_mlp(
    const float* __restrict__ xn, const float* __restrict__ p1,
    const float* __restrict__ g1b, const float* __restrict__ bt1b,
    const float* __restrict__ W1b, const float* __restrict__ b1b,
    const float* __restrict__ W2b, const float* __restrict__ b2b,
    float* __restrict__ p2)
{
  int g = blockIdx.y; int p = g/10;
  __shared__ float tmp[256], sc1[8], sh1[8];
  reduce_bn_(p1 + (size_t)g*736, 46, 1.f/11776.f, g1b+p*8, bt1b+p*8, sc1, sh1, tmp);
  const float* W1 = W1b + p*144; const float* b1 = b1b + p*8;
  const float* W2 = W2b + p*64;  const float* b2 = b2b + p*8;
  int row = blockIdx.x*256 + threadIdx.x;            // [0, 259072)
  int b = row / 506, e = row - b*506;
  int r = e / 22, jj = e - r*22;
  int s = jj + (jj>=r ? 1 : 0);
  const float* base = xn + (size_t)g*94208 + (size_t)b*184;
  float xs[8], xr[8];
  #pragma unroll
  for (int k=0;k<8;k++){ xs[k] = base[s*8+k]*sc1[k]+sh1[k]; xr[k] = base[r*8+k]*sc1[k]+sh1[k]; }
  float et0 = (jj==0 && r>=1 && r<=21) ? 1.f : 0.f;
  float et1 = (r==22) ? 1.f : 0.f;
  float h1[8], h2[8];
  #pragma unroll
  for (int j=0;j<8;j++){
    const float* w = W1 + j*18;
    float a = b1[j] + w[16]*et0 + w[17]*et1;
    #pragma unroll
    for (int k=0;k<8;k++) a += w[k]*xs[k];
    #pragma unroll
    for (int k=0;k<8;k++) a += w[8+k]*xr[k];
    h1[j] = elu_(a);
  }
  #pragma unroll
  for (int j=0;j<8;j++){
    float a = b2[j];
    #pragma unroll
    for (int k=0;k<8;k++) a += W2[j*8+k]*h1[k];
    h2[j] = elu_(a);
  }
  __shared__ float red[4][16];
  block_stats_(h2, p2 + ((size_t)g*1012 + blockIdx.x)*16, red);
}

// ---- reduce n x 16 partials -> scsh[g][16] (sc, sh) ----
__global__ __launch_bounds__(256) void k_bnred(
    const float* __restrict__ part, int n, float invN,
    const float* __restrict__ gamb, const float* __restrict__ betb,
    float* __restrict__ scsh)
{
  int g = blockIdx.x; int p = g/10;
  int tid = threadIdx.x;
  __shared__ float tmp[256];
  const float* pp = part + (size_t)g*n*16;
  int c = tid & 15, i0 = tid >> 4;
  float s = 0.f;
  for (int i = i0; i < n; i += 16) s += pp[i*16 + c];
  tmp[i0*16 + c] = s;
  __syncthreads();
  if (tid < 16){
    float v = 0.f;
    #pragma unroll
    for (int i=0;i<16;i++) v += tmp[i*16 + tid];
    tmp[tid] = v;
  }
  __syncthreads();
  if (tid < 8){
    float m = tmp[tid]*invN;
    float var = tmp[8+tid]*invN - m*m;
    float rs = rsqrtf(var + 1e-5f);
    float sc = rs*gamb[p*8+tid];
    scsh[g*16 + tid] = sc;
    scsh[g*16 + 8 + tid] = betb[p*8+tid] - m*sc;
  }
}

// ---- edge2node per-sample: 1 block per (b,g); each edge computed once ----
__global__ __launch_bounds__(512) void k_e2n(
    const float* __restrict__ xn, const float* __restrict__ p1,
    const float* __restrict__ g1b, const float* __restrict__ bt1b,
    const float* __restrict__ scsh2,
    const float* __restrict__ W1b, const float* __restrict__ b1b,
    const float* __restrict__ W2b, const float* __restrict__ b2b,
    const float* __restrict__ W3b, const float* __restrict__ b3b,
    const float* __restrict__ W4b, const float* __restrict__ b4b,
    float* __restrict__ out, float* __restrict__ p3)
{
  int g = blockIdx.y; int p = g/10; int b = blockIdx.x;
  int tid = threadIdx.x;
  __shared__ float tmp[512];
  __shared__ float sc1[8], sh1[8], sc2[8], sh2[8];
  __shared__ float xnode[207];   // 23 x 9
  __shared__ float le[4554];     // 506 x 9
  __shared__ float accs[207];    // 23 x 9
  { // BN1 reduce over 46 partials (512-thread variant)
    int c = tid & 15, i0 = tid >> 4;                 // 32 groups
    const float* pp = p1 + (size_t)g*736;
    float s = 0.f;
    for (int i = i0; i < 46; i += 32) s += pp[i*16 + c];
    tmp[i0*16 + c] = s;
    __syncthreads();
    if (tid < 16){
      float v = 0.f;
      #pragma unroll
      for (int i=0;i<32;i++) v += tmp[i*16 + tid];
      tmp[tid] = v;
    }
    __syncthreads();
    if (tid < 8){
      float m = tmp[tid]*(1.f/11776.f);
      float var = tmp[8+tid]*(1.f/11776.f) - m*m;
      float rs = rsqrtf(var + 1e-5f);
      float s2 = rs*g1b[p*8+tid];
      sc1[tid] = s2; sh1[tid] = bt1b[p*8+tid] - m*s2;
    }
    if (tid >= 8 && tid < 16){
      sc2[tid-8] = scsh2[g*16 + tid-8];
      sh2[tid-8] = scsh2[g*16 + tid];
    }
    __syncthreads();
  }
  if (tid < 184){
    int n = tid >> 3, c = tid & 7;
    float v = xn[((size_t)g*11776 + b*23 + n)*8 + c];
    xnode[n*9+c] = v*sc1[c] + sh1[c];
  }
  __syncthreads();
  if (tid < 506){
    int r = tid/22, jj = tid - r*22;
    int s = jj + (jj>=r ? 1 : 0);
    const float* W1 = W1b + p*144; const float* b1 = b1b + p*8;
    const float* W2 = W2b + p*64;  const float* b2 = b2b + p*8;
    float et0 = (jj==0 && r>=1 && r<=21) ? 1.f : 0.f;
    float et1 = (r==22) ? 1.f : 0.f;
    float h1[8];
    #pragma unroll
    for (int j=0;j<8;j++){
      const float* w = W1 + j*18;
      float a = b1[j] + w[16]*et0 + w[17]*et1;
      #pragma unroll
      for (int k=0;k<8;k++) a += w[k]*xnode[s*9+k];
      #pragma unroll
      for (int k=0;k<8;k++) a += w[8+k]*xnode[r*9+k];
      h1[j] = elu_(a);
    }
    #pragma unroll
    for (int j=0;j<8;j++){
      float a = b2[j];
      #pragma unroll
      for (int k=0;k<8;k++) a += W2[j*8+k]*h1[k];
      le[tid*9+j] = elu_(a)*sc2[j] + sh2[j];
    }
  }
  __syncthreads();
  if (tid < 184){
    int r = tid >> 3, c = tid & 7;
    const float* lp = le + r*198 + c;
    float s = 0.f;
    #pragma unroll
    for (int jj=0;jj<22;jj++) s += lp[jj*9];
    accs[r*9+c] = s;
  }
  __syncthreads();
  if (tid < 23){
    int r = tid;
    const float inv23 = 1.f/23.f;
    float xk[8];
    #pragma unroll
    for (int k=0;k<8;k++) xk[k] = accs[r*9+k]*inv23;
    float nt0 = (r<22)?inv23:0.f, nt1 = (r==22)?inv23:0.f;
    const float* W3 = W3b + p*80; const float* b3 = b3b + p*8;
    const float* W4 = W4b + p*64; const float* b4 = b4b + p*8;
    float h1b[8];
    #pragma unroll
    for (int j=0;j<8;j++){
      const float* w = W3 + j*10;
      float a = b3[j] + w[8]*nt0 + w[9]*nt1;
      #pragma unroll
      for (int k=0;k<8;k++) a += w[k]*xk[k];
      h1b[j] = elu_(a);
    }
    #pragma unroll
    for (int j=0;j<8;j++){
      float a = b4[j];
      #pragma unroll
      for (int k=0;k<8;k++) a += W4[j*8+k]*h1b[k];
      float o = elu_(a);
      out[((size_t)g*11776 + b*23 + r)*8 + j] = o;
      accs[r*9+j] = o;
    }
  }
  __syncthreads();
  if (tid < 16){
    int c = tid & 7; bool sq = tid >= 8;
    float s = 0.f;
    #pragma unroll
    for (int r=0;r<23;r++){ float v = accs[r*9+c]; s += sq ? v*v : v; }
    p3[((size_t)g*512 + b)*16 + tid] = s;
  }
}

// ---- apply BN3 to precomputed g3 ----
__global__ __launch_bounds__(256) void k_bn_apply3(
    float* __restrict__ buf, const float* __restrict__ scsh3)
{
  int g = blockIdx.y;
  __shared__ float sc[8], sh[8];
  if (threadIdx.x < 8){
    sc[threadIdx.x] = scsh3[g*16 + threadIdx.x];
    sh[threadIdx.x] = scsh3[g*16 + 8 + threadIdx.x];
  }
  __syncthreads();
  int e = blockIdx.x*256 + threadIdx.x;              // [0, 94208)
  float* pp = buf + (size_t)g*94208 + e;
  *pp = (*pp)*sc[e&7] + sh[e&7];
}

// ---- heads: split-K tiled GEMM -> partials rawp[8][4][512][92] ----
__global__ __launch_bounds__(256) void k_heads(
    const float* __restrict__ gy, const float* __restrict__ gx,
    const float* __restrict__ h,
    const float* __restrict__ Wpm, const float* __restrict__ Wps,
    const float* __restrict__ Wem, const float* __restrict__ Wes,
    float* __restrict__ rawp)
{
  int head = blockIdx.y;
  const float* W  = (head==0)?Wpm:(head==1)?Wps:(head==2)?Wem:Wes;
  const float* gsel = (head<2)?gy:gx;
  int b0 = blockIdx.x*64;
  int kbeg = blockIdx.z*199, kend = kbeg+199;
  __shared__ float As[16][68];
  __shared__ float Ws[16][100];
  int tid = threadIdx.x;
  int tb = tid & 15, tj = tid >> 4;
  float acc[4][6];
  #pragma unroll
  for (int u=0;u<4;u++)
    #pragma unroll
    for (int vv=0;vv<6;vv++) acc[u][vv]=0.f;
  for (int k0=kbeg; k0<kend; k0+=16){
    #pragma unroll
    for (int l=0;l<4;l++){
      int lin = tid + 256*l;
      int kk = lin & 15, bl = lin >> 4;
      int i = k0 + kk;
      float v = 0.f;
      if (i < kend){
        int bb = b0 + bl;
        if (i < 184) v = gsel[bb*184 + i];
        else { int i2 = i - 184; v = h[(size_t)(i2>>6)*32768 + bb*64 + (i2&63)]; }
      }
      As[kk][bl] = v;
    }
    #pragma unroll
    for (int l=0;l<6;l++){
      int lin = tid + 256*l;
      int kk = lin & 15, jl = lin >> 4;
      int i = k0 + kk;
      float v = 0.f;
      if (i < kend && jl < 92) v = W[jl*1592 + i];
      Ws[kk][jl] = v;
    }
    __syncthreads();
    #pragma unroll
    for (int kk=0;kk<16;kk++){
      float4 a4 = *(const float4*)&As[kk][tb*4];
      float av[4] = {a4.x,a4.y,a4.z,a4.w};
      float wv[6];
      #pragma unroll
      for (int vv=0;vv<6;vv++) wv[vv] = Ws[kk][tj + 16*vv];
      #pragma unroll
      for (int u=0;u<4;u++)
        #pragma unroll
        for (int vv=0;vv<6;vv++) acc[u][vv] += av[u]*wv[vv];
    }
    __syncthreads();
  }
  float* dst = rawp + (size_t)blockIdx.z*188416 + (size_t)head*47104;
  #pragma unroll
  for (int u=0;u<4;u++){
    int bb = b0 + tb*4 + u;
    #pragma unroll
    for (int vv=0;vv<6;vv++){
      int j = tj + 16*vv;
      if (j < 92) dst[bb*92 + j] = acc[u][vv];
    }
  }
}

// ---- fused: split-K combine + bias + sample + KLD + node MLP1 (set 2) ----
__global__ __launch_bounds__(256) void k_fused(
    const float* __restrict__ rawp,
    const float* __restrict__ bpm, const float* __restrict__ bps,
    const float* __restrict__ bem, const float* __restrict__ bes,
    const float* __restrict__ eps_t, float* __restrict__ z,
    float* __restrict__ lklp,
    const float* __restrict__ W1, const float* __restrict__ b1,
    const float* __restrict__ W2, const float* __restrict__ b2,
    float* __restrict__ out, float* __restrict__ part)
{
  int tid = threadIdx.x;
  int row = blockIdx.x*256 + tid;                    // [0, 11776)
  int bb = row/23, n = row - bb*23;
  (void)bb;
  float pm[4]={0,0,0,0}, ps[4]={0,0,0,0}, em[4]={0,0,0,0}, es[4]={0,0,0,0};
  const float* rp = rawp + 4*(size_t)row;
  #pragma unroll
  for (int zz=0;zz<8;zz++){
    const float* q = rp + (size_t)zz*188416;
    float4 a = *(const float4*)(q);
    float4 bq = *(const float4*)(q + 47104);
    float4 c = *(const float4*)(q + 94208);
    float4 d = *(const float4*)(q + 141312);
    pm[0]+=a.x; pm[1]+=a.y; pm[2]+=a.z; pm[3]+=a.w;
    ps[0]+=bq.x; ps[1]+=bq.y; ps[2]+=bq.z; ps[3]+=bq.w;
    em[0]+=c.x; em[1]+=c.y; em[2]+=c.z; em[3]+=c.w;
    es[0]+=d.x; es[1]+=d.y; es[2]+=d.z; es[3]+=d.w;
  }
  int j0 = 4*n;
  float4 e4 = *(const float4*)(eps_t + 4*(size_t)row);
  float ev[4] = {e4.x, e4.y, e4.z, e4.w};
  float zv[4]; float kl = 0.f;
  #pragma unroll
  for (int q=0;q<4;q++){
    float PM = pm[q] + bpm[j0+q];
    float PS = sp_(ps[q] + bps[j0+q]);
    float EM = em[q] + bem[j0+q];
    float ES = sp_(es[q] + bes[j0+q]);
    zv[q] = EM + ES*ev[q];
    float d = EM - PM;
    kl += 0.5f*(2.f*logf(PS/ES) + (ES*ES + d*d)/(PS*PS) - 1.f);
  }
  float4 zq; zq.x=zv[0]; zq.y=zv[1]; zq.z=zv[2]; zq.w=zv[3];
  *(float4*)(z + 4*(size_t)row) = zq;
  __shared__ float redk[4];
  float ks = wsum_(kl);
  if ((tid&63)==0) redk[tid>>6] = ks;
  __syncthreads();
  if (tid==0) lklp[blockIdx.x] = redk[0]+redk[1]+redk[2]+redk[3];
  // node MLP1 on z (param set 2 pointers passed directly)
  float h1[8], h2[8];
  #pragma unroll
  for (int j=0;j<8;j++){
    float a = b1[j] + W1[j*4+0]*zv[0] + W1[j*4+1]*zv[1] + W1[j*4+2]*zv[2] + W1[j*4+3]*zv[3];
    h1[j] = elu_(a);
  }
  #pragma unroll
  for (int j=0;j<8;j++){
    float a = b2[j];
    #pragma unroll
    for (int k=0;k<8;k++) a += W2[j*8+k]*h1[k];
    h2[j] = elu_(a);
    out[(size_t)row*8 + j] = h2[j];
  }
  __shared__ float red[4][16];
  block_stats_(h2, part + (size_t)blockIdx.x*16, red);
}

// ---- dec heads, BN3 fused inline (reduce 512 per-sample partials) ----
__global__ __launch_bounds__(256) void k_dec(
    const float* __restrict__ zg3, const float* __restrict__ p3,
    const float* __restrict__ gam, const float* __restrict__ bet,
    const float* __restrict__ Wm, const float* __restrict__ Bm,
    const float* __restrict__ Wsd, const float* __restrict__ Bsd,
    float* __restrict__ odm, float* __restrict__ ods)
{
  __shared__ float tmp[256], sc[8], sh[8];
  reduce_bn_(p3, 512, 1.f/11776.f, gam, bet, sc, sh, tmp);
  int idx = blockIdx.x*256 + threadIdx.x;            // [0, 90112)
  int hd = idx / 45056; int rem = idx - hd*45056;
  int b = rem / 88, j = rem - b*88;
  const float* W = hd ? Wsd : Wm;
  const float* a = zg3 + (size_t)b*184;
  float accv = hd ? Bsd[j] : Bm[j];
  for (int i=0;i<184;i++){
    float x = a[i]*sc[i&7] + sh[i&7];
    accv += W[j*184+i]*x;
  }
  if (hd) ods[(size_t)b*88+j] = sp_(accv);
  else    odm[(size_t)b*88+j] = accv;
}

// ---- per-agent GRU update (in place) ----
__global__ __launch_bounds__(256) void k_gru(
    float* __restrict__ h, const float* __restrict__ x_t,
    const float* __restrict__ z, const float* __restrict__ Wih,
    const float* __restrict__ Whh, const float* __restrict__ bih,
    const float* __restrict__ bhh)
{
  int a = blockIdx.x;
  __shared__ float Wh[12288];
  __shared__ float Wi[1728];
  __shared__ float hs[4][64];
  __shared__ float gins[4][8];
  int c = threadIdx.x, bl = threadIdx.y;
  int tid = bl*64 + c;
  const float* Wg = Whh + (size_t)a*12288;
  for (int i=tid;i<12288;i+=256) Wh[i] = Wg[i];
  const float* Wig = Wih + (size_t)a*1536;
  for (int i=tid;i<1536;i+=256) Wi[(i/8)*9 + (i&7)] = Wig[i];
  float bi0 = bih[a*192+c], bi1 = bih[a*192+64+c], bi2 = bih[a*192+128+c];
  float bh0 = bhh[a*192+c], bh1 = bhh[a*192+64+c], bh2 = bhh[a*192+128+c];
  for (int bc=0;bc<8;bc++){
    int b = blockIdx.y*32 + bc*4 + bl;
    __syncthreads();
    hs[bl][c] = h[((size_t)a*512 + b)*64 + c];
    if (c < 8) gins[bl][c] = (c<4) ? x_t[b*92 + a*4 + c] : z[b*92 + a*4 + (c-4)];
    __syncthreads();
    float g0=bi0, g1=bi1, g2=bi2;
    #pragma unroll
    for (int k=0;k<8;k++){
      float xv = gins[bl][k];
      g0 += Wi[c*9+k]*xv;
      g1 += Wi[(64+c)*9+k]*xv;
      g2 += Wi[(128+c)*9+k]*xv;
    }
    float q0=bh0, q1=bh1, q2=bh2;
    for (int kk=0;kk<64;kk++){
      int k = (kk + c) & 63;
      float hv = hs[bl][k];
      q0 += Wh[c*64+k]*hv;
      q1 += Wh[(64+c)*64+k]*hv;
      q2 += Wh[(128+c)*64+k]*hv;
    }
    float rg = sig_(g0+q0);
    float zg = sig_(g1+q1);
    float ng = tanhf(g2 + rg*q2);
    h[((size_t)a*512 + b)*64 + c] = (1.f-zg)*ng + zg*hs[bl][c];
  }
}

__global__ __launch_bounds__(256) void k_final(const float* __restrict__ lklp,
                                               float* __restrict__ out){
  __shared__ float red[4];
  float s = 0.f;
  for (int i = threadIdx.x; i < 460; i += 256) s += lklp[i];
  s = wsum_(s);
  if ((threadIdx.x&63)==0) red[threadIdx.x>>6]=s;
  __syncthreads();
  if (threadIdx.x==0) out[0] = red[0]+red[1]+red[2]+red[3];
}

extern "C" void kernel_launch(void* const* d_in, const int* in_sizes, int n_in,
                              void* d_out, int out_size, void* d_ws, size_t ws_size,
                              hipStream_t stream)
{
  (void)in_sizes; (void)n_in; (void)out_size; (void)ws_size;
  const float* states=(const float*)d_in[0];
  const float* eps   =(const float*)d_in[1];
  const float *m1W1=(const float*)d_in[2],  *m1b1=(const float*)d_in[3],
              *m1W2=(const float*)d_in[4],  *m1b2=(const float*)d_in[5],
              *m1g =(const float*)d_in[6],  *m1bt=(const float*)d_in[7];
  const float *m2W1=(const float*)d_in[8],  *m2b1=(const float*)d_in[9],
              *m2W2=(const float*)d_in[10], *m2b2=(const float*)d_in[11],
              *m2g =(const float*)d_in[12], *m2bt=(const float*)d_in[13];
  const float *m3W1=(const float*)d_in[14], *m3b1=(const float*)d_in[15],
              *m3W2=(const float*)d_in[16], *m3b2=(const float*)d_in[17],
              *m3g =(const float*)d_in[18], *m3bt=(const float*)d_in[19];
  const float *emW=(const float*)d_in[20], *emB=(const float*)d_in[21];
  const float *esW=(const float*)d_in[22], *esB=(const float*)d_in[23];
  const float *pmW=(const float*)d_in[24], *pmB=(const float*)d_in[25];
  const float *psW=(const float*)d_in[26], *psB=(const float*)d_in[27];
  const float *dmW=(const float*)d_in[28], *dmB=(const float*)d_in[29];
  const float *dsW=(const float*)d_in[30], *dsB=(const float*)d_in[31];
  const float *gWih=(const float*)d_in[32], *gWhh=(const float*)d_in[33];
  const float *gbih=(const float*)d_in[34], *gbhh=(const float*)d_in[35];
  float* out = (float*)d_out;
  float* ws  = (float*)d_ws;

  // persistent (floats)
  float* g3     = ws;                 // [20][11776][8] = 1,884,160
  float* h      = ws + 1884160;       // [22][512][64]  = 720,896
  float* zb     = ws + 2605056;       // [512][92]      = 47,104
  float* lklp   = ws + 2652160;       // 460
  float* scsh2  = ws + 2652620;       // [20][16] = 320
  float* scsh3  = ws + 2652940;       // [20][16] = 320
  float* zscsh2 = ws + 2653260;       // 16
  float* scr    = ws + 2653276;
  // precompute view of scr
  float* xn  = scr;                   // [20][11776][8] = 1,884,160
  float* p1p = scr + 1884160;         // [20][46][16]   = 14,720
  float* p2p = scr + 1898880;         // [20][1012][16] = 323,840
  float* p3p = scr + 1898880;         // [20][512][16]  = 163,840 (aliases p2p; p2p dead)
  // loop view of scr (stream-ordered reuse)
  float* rawp = scr;                  // [8][4][512][92] = 1,507,328
  float* zxn  = scr + 1507328;        // 94,208
  float* zg3  = scr + 1601536;        // 94,208
  float* zp1  = scr + 1695744;        // [46][16]  = 736
  float* zp2  = scr + 1696480;        // [1012][16]= 16,192
  float* zp3  = scr + 1712672;        // [512][16] = 8,192
  // total: 2,653,276 + 2,222,720 = 4,875,996 floats = 19.5 MB

  hipMemsetAsync(h, 0, 720896*sizeof(float), stream);

  // ---- precompute gnn(y,p=0)/gnn(x,p=1) for all t (g = p*10+t) ----
  k_pre_mlp1<<<dim3(46,20),256,0,stream>>>(states, xn, m1W1, m1b1, m1W2, m1b2, p1p);
  k_edge_mlp<<<dim3(1012,20),256,0,stream>>>(xn, p1p, m1g, m1bt,
      m2W1, m2b1, m2W2, m2b2, p2p);
  k_bnred<<<20,256,0,stream>>>(p2p, 1012, 1.f/259072.f, m2g, m2bt, scsh2);
  k_e2n<<<dim3(512,20),512,0,stream>>>(xn, p1p, m1g, m1bt, scsh2,
      m2W1, m2b1, m2W2, m2b2, m3W1, m3b1, m3W2, m3b2, g3, p3p);
  k_bnred<<<20,256,0,stream>>>(p3p, 512, 1.f/11776.f, m3g, m3bt, scsh3);
  k_bn_apply3<<<dim3(368,20),256,0,stream>>>(g3, scsh3);

  // ---- sequential scan ----
  for (int t=0;t<10;t++){
    k_heads<<<dim3(8,4,8),256,0,stream>>>(g3 + (size_t)t*94208,
        g3 + 942080 + (size_t)t*94208, h, pmW, psW, emW, esW, rawp);
    k_fused<<<46,256,0,stream>>>(rawp, pmB, psB, emB, esB,
        eps + (size_t)t*47104, zb, lklp + t*46,
        m1W1+64, m1b1+16, m1W2+128, m1b2+16, zxn, zp1);
    k_edge_mlp<<<dim3(1012,1),256,0,stream>>>(zxn, zp1, m1g+16, m1bt+16,
        m2W1+288, m2b1+16, m2W2+128, m2b2+16, zp2);
    k_bnred<<<1,256,0,stream>>>(zp2, 1012, 1.f/259072.f, m2g+16, m2bt+16, zscsh2);
    k_e2n<<<dim3(512,1),512,0,stream>>>(zxn, zp1, m1g+16, m1bt+16, zscsh2,
        m2W1+288, m2b1+16, m2W2+128, m2b2+16,
        m3W1+160, m3b1+16, m3W2+128, m3b2+16, zg3, zp3);
    k_dec<<<352,256,0,stream>>>(zg3, zp3, m3g+16, m3bt+16,
        dmW, dmB, dsW, dsB, out + (size_t)t*45056, out + 450560 + (size_t)t*45056);
    k_gru<<<dim3(22,16),dim3(64,4),0,stream>>>(h, states + (size_t)(t+1)*47104, zb,
        gWih, gWhh, gbih, gbhh);
  }
  k_final<<<1,256,0,stream>>>(lklp, out + 901120);
}

// Round 4
// 1725.292 us; speedup vs baseline: 10.4681x; 1.1513x over previous
//
#include <hip/hip_runtime.h>
#include <math.h>

// T=10 B=512 N_ALL=23 N_AGENTS=22 NH=8 E=506 RNN_H=64 Z_DIM=92 IN_H=1592
// node rows/group: 11776 ; gnn slice: 94208 floats

__device__ __forceinline__ float elu_(float x){ return x>0.f ? x : __expf(x)-1.f; }
__device__ __forceinline__ float sp_(float x){ return fmaxf(x,0.f)+log1pf(__expf(-fabsf(x))); }
__device__ __forceinline__ float sig_(float x){ return 1.f/(1.f+__expf(-x)); }
__device__ __forceinline__ float wsum_(float v){
  #pragma unroll
  for (int o=32;o;o>>=1) v += __shfl_down(v,o,64);
  return v;
}

// 256-thr block: reduce n x 16 partials -> BN scale/shift in LDS
__device__ __forceinline__ void reduce_bn_(const float* __restrict__ part, int n,
    float invN, const float* __restrict__ gam, const float* __restrict__ bet,
    float* sc, float* sh, float* tmp)
{
  int tid = threadIdx.x;
  int c = tid & 15, i0 = tid >> 4;
  float s = 0.f;
  for (int i = i0; i < n; i += 16) s += part[i*16 + c];
  tmp[i0*16 + c] = s;
  __syncthreads();
  if (tid < 16){
    float v = 0.f;
    #pragma unroll
    for (int i=0;i<16;i++) v += tmp[i*16 + tid];
    tmp[tid] = v;
  }
  __syncthreads();
  if (tid < 8){
    float m = tmp[tid]*invN;
    float var = tmp[8+tid]*invN - m*m;
    float rs = rsqrtf(var + 1e-5f);
    float s2 = rs*gam[tid];
    sc[tid] = s2; sh[tid] = bet[tid] - m*s2;
  }
  __syncthreads();
}

// 256-thr block stats: h[8]/thread -> part[16] = {sum8, sumsq8}
__device__ __forceinline__ void block_stats_(const float h[8], float* __restrict__ part,
                                             float red[4][16])
{
  int wid = threadIdx.x >> 6, lane = threadIdx.x & 63;
  #pragma unroll
  for (int j=0;j<8;j++){
    float a = wsum_(h[j]);
    float b = wsum_(h[j]*h[j]);
    if (lane==0){ red[wid][j]=a; red[wid][8+j]=b; }
  }
  __syncthreads();
  if (threadIdx.x < 16)
    part[threadIdx.x] = red[0][threadIdx.x]+red[1][threadIdx.x]
                       +red[2][threadIdx.x]+red[3][threadIdx.x];
}

// ---- MLP1 stats only (precompute; g = p*10+t) ----
__global__ __launch_bounds__(256) void k_stats1(
    const float* __restrict__ states,
    const float* __restrict__ W1b, const float* __restrict__ b1b,
    const float* __restrict__ W2b, const float* __restrict__ b2b,
    float* __restrict__ part)
{
  int g = blockIdx.y; int p = g/10; int t = g - p*10;
  const float* W1 = W1b + p*32; const float* b1 = b1b + p*8;
  const float* W2 = W2b + p*64; const float* b2 = b2b + p*8;
  int row = blockIdx.x*256 + threadIdx.x;            // [0, 11776)
  float4 x4 = *(const float4*)(states + (size_t)(t+p)*47104 + 4*(size_t)row);
  float h1[8], h2[8];
  #pragma unroll
  for (int j=0;j<8;j++){
    float a = b1[j] + W1[j*4+0]*x4.x + W1[j*4+1]*x4.y + W1[j*4+2]*x4.z + W1[j*4+3]*x4.w;
    h1[j] = elu_(a);
  }
  #pragma unroll
  for (int j=0;j<8;j++){
    float a = b2[j];
    #pragma unroll
    for (int k=0;k<8;k++) a += W2[j*8+k]*h1[k];
    h2[j] = elu_(a);
  }
  __shared__ float red[4][16];
  block_stats_(h2, part + ((size_t)g*46 + blockIdx.x)*16, red);
}

// ---- per-sample: MLP1 (recomputed) + BN1 + edge MLP (once) -> receiver sums + BN2 stats ----
__global__ __launch_bounds__(512) void k_gnn_edges(
    const float* __restrict__ src, long sstride, const float* __restrict__ p1,
    const float* __restrict__ nW1b, const float* __restrict__ nb1b,
    const float* __restrict__ nW2b, const float* __restrict__ nb2b,
    const float* __restrict__ g1b, const float* __restrict__ bt1b,
    const float* __restrict__ eW1b, const float* __restrict__ eb1b,
    const float* __restrict__ eW2b, const float* __restrict__ eb2b,
    float* __restrict__ nodeacc, float* __restrict__ p2)
{
  int g = blockIdx.y; int p = g/10; int t = g - p*10; int b = blockIdx.x;
  int tid = threadIdx.x;
  __shared__ float tmp[512];
  __shared__ float sc1[8], sh1[8];
  __shared__ float xnode[207];   // 23 x 9
  __shared__ float le[4554];     // 506 x 9
  __shared__ float accs[207];    // 23 x 9
  __shared__ float redsq[8][8];
  { // BN1 reduce over 46 partials, 512 threads
    const float* pp = p1 + (size_t)g*736;
    int c = tid & 15, i0 = tid >> 4;                 // 32 groups
    float s = 0.f;
    for (int i = i0; i < 46; i += 32) s += pp[i*16 + c];
    tmp[i0*16 + c] = s;
    __syncthreads();
    if (tid < 16){
      float v = 0.f;
      #pragma unroll
      for (int i=0;i<32;i++) v += tmp[i*16 + tid];
      tmp[tid] = v;
    }
    __syncthreads();
    if (tid < 8){
      float m = tmp[tid]*(1.f/11776.f);
      float var = tmp[8+tid]*(1.f/11776.f) - m*m;
      float rs = rsqrtf(var + 1e-5f);
      float s2 = rs*g1b[p*8+tid];
      sc1[tid] = s2; sh1[tid] = bt1b[p*8+tid] - m*s2;
    }
    __syncthreads();
  }
  if (tid < 23){ // node MLP1 + BN1
    const float* x = src + (size_t)(t+p)*sstride + (size_t)b*92 + tid*4;
    const float* W1 = nW1b + p*32; const float* b1 = nb1b + p*8;
    const float* W2 = nW2b + p*64; const float* b2 = nb2b + p*8;
    float x0=x[0], x1=x[1], x2=x[2], x3=x[3];
    float h1[8], h2[8];
    #pragma unroll
    for (int j=0;j<8;j++){
      float a = b1[j] + W1[j*4+0]*x0 + W1[j*4+1]*x1 + W1[j*4+2]*x2 + W1[j*4+3]*x3;
      h1[j] = elu_(a);
    }
    #pragma unroll
    for (int j=0;j<8;j++){
      float a = b2[j];
      #pragma unroll
      for (int k=0;k<8;k++) a += W2[j*8+k]*h1[k];
      h2[j] = elu_(a);
      xnode[tid*9+j] = h2[j]*sc1[j] + sh1[j];
    }
  }
  __syncthreads();
  float sq[8] = {0,0,0,0,0,0,0,0};
  if (tid < 506){
    int r = tid/22, jj = tid - r*22;
    int s = jj + (jj>=r ? 1 : 0);
    const float* W1 = eW1b + p*144; const float* b1 = eb1b + p*8;
    const float* W2 = eW2b + p*64;  const float* b2 = eb2b + p*8;
    float et0 = (jj==0 && r>=1 && r<=21) ? 1.f : 0.f;
    float et1 = (r==22) ? 1.f : 0.f;
    float h1[8];
    #pragma unroll
    for (int j=0;j<8;j++){
      const float* w = W1 + j*18;
      float a = b1[j] + w[16]*et0 + w[17]*et1;
      #pragma unroll
      for (int k=0;k<8;k++) a += w[k]*xnode[s*9+k];
      #pragma unroll
      for (int k=0;k<8;k++) a += w[8+k]*xnode[r*9+k];
      h1[j] = elu_(a);
    }
    #pragma unroll
    for (int j=0;j<8;j++){
      float a = b2[j];
      #pragma unroll
      for (int k=0;k<8;k++) a += W2[j*8+k]*h1[k];
      float h2 = elu_(a);
      le[tid*9+j] = h2;
      sq[j] = h2*h2;
    }
  }
  int wid = tid >> 6, lane = tid & 63;
  #pragma unroll
  for (int j=0;j<8;j++){
    float v = wsum_(sq[j]);
    if (lane==0) redsq[wid][j] = v;
  }
  __syncthreads();
  if (tid < 184){ // per-receiver pre-BN sums
    int r = tid >> 3, c = tid & 7;
    const float* lp = le + r*198 + c;
    float s = 0.f;
    #pragma unroll
    for (int jj=0;jj<22;jj++) s += lp[jj*9];
    accs[r*9+c] = s;
    nodeacc[((size_t)g*512 + b)*184 + tid] = s;
  }
  __syncthreads();
  if (tid < 16){
    int c = tid & 7;
    float s = 0.f;
    if (tid < 8){
      #pragma unroll
      for (int r=0;r<23;r++) s += accs[r*9+c];
    } else {
      #pragma unroll
      for (int w=0;w<8;w++) s += redsq[w][c];
    }
    p2[((size_t)g*512 + b)*16 + tid] = s;
  }
}

// ---- BN2 analytic + MLP3 -> pre-BN g3 + BN3 partials ----
__global__ __launch_bounds__(256) void k_gnn_node3(
    const float* __restrict__ nodeacc, const float* __restrict__ p2,
    const float* __restrict__ g2b, const float* __restrict__ bt2b,
    const float* __restrict__ W3b, const float* __restrict__ b3b,
    const float* __restrict__ W4b, const float* __restrict__ b4b,
    float* __restrict__ out, float* __restrict__ p3)
{
  int g = blockIdx.y; int p = g/10;
  __shared__ float tmp[256], sc2[8], sh2[8];
  reduce_bn_(p2 + (size_t)g*8192, 512, 1.f/259072.f, g2b+p*8, bt2b+p*8, sc2, sh2, tmp);
  int row = blockIdx.x*256 + threadIdx.x;            // [0, 11776)
  int b = row/23, r = row - b*23;
  const float inv23 = 1.f/23.f;
  const float* na = nodeacc + ((size_t)g*512 + b)*184 + r*8;
  float xk[8];
  #pragma unroll
  for (int k=0;k<8;k++) xk[k] = (na[k]*sc2[k] + 22.f*sh2[k]) * inv23;
  float nt0 = (r<22)?inv23:0.f, nt1 = (r==22)?inv23:0.f;
  const float* W3 = W3b + p*80; const float* b3 = b3b + p*8;
  const float* W4 = W4b + p*64; const float* b4 = b4b + p*8;
  float h1b[8], o[8];
  #pragma unroll
  for (int j=0;j<8;j++){
    const float* w = W3 + j*10;
    float a = b3[j] + w[8]*nt0 + w[9]*nt1;
    #pragma unroll
    for (int k=0;k<8;k++) a += w[k]*xk[k];
    h1b[j] = elu_(a);
  }
  #pragma unroll
  for (int j=0;j<8;j++){
    float a = b4[j];
    #pragma unroll
    for (int k=0;k<8;k++) a += W4[j*8+k]*h1b[k];
    o[j] = elu_(a);
    out[((size_t)g*11776 + row)*8 + j] = o[j];
  }
  __shared__ float red[4][16];
  block_stats_(o, p3 + ((size_t)g*46 + blockIdx.x)*16, red);
}

// ---- reduce n x 16 partials -> scsh[g][16] ----
__global__ __launch_bounds__(256) void k_bnred(
    const float* __restrict__ part, int n, float invN,
    const float* __restrict__ gamb, const float* __restrict__ betb,
    float* __restrict__ scsh)
{
  int g = blockIdx.x; int p = g/10;
  int tid = threadIdx.x;
  __shared__ float tmp[256];
  const float* pp = part + (size_t)g*n*16;
  int c = tid & 15, i0 = tid >> 4;
  float s = 0.f;
  for (int i = i0; i < n; i += 16) s += pp[i*16 + c];
  tmp[i0*16 + c] = s;
  __syncthreads();
  if (tid < 16){
    float v = 0.f;
    #pragma unroll
    for (int i=0;i<16;i++) v += tmp[i*16 + tid];
    tmp[tid] = v;
  }
  __syncthreads();
  if (tid < 8){
    float m = tmp[tid]*invN;
    float var = tmp[8+tid]*invN - m*m;
    float rs = rsqrtf(var + 1e-5f);
    float sc = rs*gamb[p*8+tid];
    scsh[g*16 + tid] = sc;
    scsh[g*16 + 8 + tid] = betb[p*8+tid] - m*sc;
  }
}

// ---- heads: split-K tiled GEMM, BN3 applied during A staging ----
__global__ __launch_bounds__(256) void k_heads(
    const float* __restrict__ gy, const float* __restrict__ gx,
    const float* __restrict__ scsh3, int t,
    const float* __restrict__ h,
    const float* __restrict__ Wpm, const float* __restrict__ Wps,
    const float* __restrict__ Wem, const float* __restrict__ Wes,
    float* __restrict__ rawp)
{
  int head = blockIdx.y;
  const float* W  = (head==0)?Wpm:(head==1)?Wps:(head==2)?Wem:Wes;
  const float* gsel = (head<2)?gy:gx;
  int sel = (head<2) ? t : 10+t;
  __shared__ float s3[16];
  __shared__ float As[16][68];
  __shared__ float Ws[16][100];
  int tid = threadIdx.x;
  if (tid < 16) s3[tid] = scsh3[sel*16 + tid];
  int b0 = blockIdx.x*64;
  int kbeg = blockIdx.z*199, kend = kbeg+199;
  int tb = tid & 15, tj = tid >> 4;
  float acc[4][6];
  #pragma unroll
  for (int u=0;u<4;u++)
    #pragma unroll
    for (int vv=0;vv<6;vv++) acc[u][vv]=0.f;
  __syncthreads();
  for (int k0=kbeg; k0<kend; k0+=16){
    #pragma unroll
    for (int l=0;l<4;l++){
      int lin = tid + 256*l;
      int kk = lin & 15, bl = lin >> 4;
      int i = k0 + kk;
      float v = 0.f;
      if (i < kend){
        int bb = b0 + bl;
        if (i < 184){ int c = i&7; v = gsel[bb*184 + i]*s3[c] + s3[8+c]; }
        else { int i2 = i - 184; v = h[(size_t)(i2>>6)*32768 + bb*64 + (i2&63)]; }
      }
      As[kk][bl] = v;
    }
    #pragma unroll
    for (int l=0;l<6;l++){
      int lin = tid + 256*l;
      int kk = lin & 15, jl = lin >> 4;
      int i = k0 + kk;
      float v = 0.f;
      if (i < kend && jl < 92) v = W[jl*1592 + i];
      Ws[kk][jl] = v;
    }
    __syncthreads();
    #pragma unroll
    for (int kk=0;kk<16;kk++){
      float4 a4 = *(const float4*)&As[kk][tb*4];
      float av[4] = {a4.x,a4.y,a4.z,a4.w};
      float wv[6];
      #pragma unroll
      for (int vv=0;vv<6;vv++) wv[vv] = Ws[kk][tj + 16*vv];
      #pragma unroll
      for (int u=0;u<4;u++)
        #pragma unroll
        for (int vv=0;vv<6;vv++) acc[u][vv] += av[u]*wv[vv];
    }
    __syncthreads();
  }
  float* dst = rawp + (size_t)blockIdx.z*188416 + (size_t)head*47104;
  #pragma unroll
  for (int u=0;u<4;u++){
    int bb = b0 + tb*4 + u;
    #pragma unroll
    for (int vv=0;vv<6;vv++){
      int j = tj + 16*vv;
      if (j < 92) dst[bb*92 + j] = acc[u][vv];
    }
  }
}

// ---- fused: split-K combine + bias + sample + KLD + MLP1(set2) stats ----
__global__ __launch_bounds__(256) void k_fused(
    const float* __restrict__ rawp,
    const float* __restrict__ bpm, const float* __restrict__ bps,
    const float* __restrict__ bem, const float* __restrict__ bes,
    const float* __restrict__ eps_t, float* __restrict__ z,
    float* __restrict__ lklp,
    const float* __restrict__ W1, const float* __restrict__ b1,
    const float* __restrict__ W2, const float* __restrict__ b2,
    float* __restrict__ part)
{
  int tid = threadIdx.x;
  int row = blockIdx.x*256 + tid;                    // [0, 11776)
  int bb = row/23, n = row - bb*23;
  (void)bb;
  float pm[4]={0,0,0,0}, ps[4]={0,0,0,0}, em[4]={0,0,0,0}, es[4]={0,0,0,0};
  const float* rp = rawp + 4*(size_t)row;
  #pragma unroll
  for (int zz=0;zz<8;zz++){
    const float* q = rp + (size_t)zz*188416;
    float4 a = *(const float4*)(q);
    float4 bq = *(const float4*)(q + 47104);
    float4 c = *(const float4*)(q + 94208);
    float4 d = *(const float4*)(q + 141312);
    pm[0]+=a.x; pm[1]+=a.y; pm[2]+=a.z; pm[3]+=a.w;
    ps[0]+=bq.x; ps[1]+=bq.y; ps[2]+=bq.z; ps[3]+=bq.w;
    em[0]+=c.x; em[1]+=c.y; em[2]+=c.z; em[3]+=c.w;
    es[0]+=d.x; es[1]+=d.y; es[2]+=d.z; es[3]+=d.w;
  }
  int j0 = 4*n;
  float4 e4 = *(const float4*)(eps_t + 4*(size_t)row);
  float ev[4] = {e4.x, e4.y, e4.z, e4.w};
  float zv[4]; float kl = 0.f;
  #pragma unroll
  for (int q=0;q<4;q++){
    float PM = pm[q] + bpm[j0+q];
    float PS = sp_(ps[q] + bps[j0+q]);
    float EM = em[q] + bem[j0+q];
    float ES = sp_(es[q] + bes[j0+q]);
    zv[q] = EM + ES*ev[q];
    float d = EM - PM;
    kl += 0.5f*(2.f*logf(PS/ES) + (ES*ES + d*d)/(PS*PS) - 1.f);
  }
  float4 zq; zq.x=zv[0]; zq.y=zv[1]; zq.z=zv[2]; zq.w=zv[3];
  *(float4*)(z + 4*(size_t)row) = zq;
  __shared__ float redk[4];
  float ks = wsum_(kl);
  if ((tid&63)==0) redk[tid>>6] = ks;
  __syncthreads();
  if (tid==0) lklp[blockIdx.x] = redk[0]+redk[1]+redk[2]+redk[3];
  float h1[8], h2[8];
  #pragma unroll
  for (int j=0;j<8;j++){
    float a = b1[j] + W1[j*4+0]*zv[0] + W1[j*4+1]*zv[1] + W1[j*4+2]*zv[2] + W1[j*4+3]*zv[3];
    h1[j] = elu_(a);
  }
  #pragma unroll
  for (int j=0;j<8;j++){
    float a = b2[j];
    #pragma unroll
    for (int k=0;k<8;k++) a += W2[j*8+k]*h1[k];
    h2[j] = elu_(a);
  }
  __shared__ float red[4][16];
  block_stats_(h2, part + (size_t)blockIdx.x*16, red);
}

// ---- tail: blocks [0,352) dec (BN3 inline), [352,704) per-agent GRU ----
__global__ __launch_bounds__(256) void k_tail(
    const float* __restrict__ zg3, const float* __restrict__ p3,
    const float* __restrict__ gam, const float* __restrict__ bet,
    const float* __restrict__ Wm, const float* __restrict__ Bm,
    const float* __restrict__ Wsd, const float* __restrict__ Bsd,
    float* __restrict__ odm, float* __restrict__ ods,
    float* __restrict__ h, const float* __restrict__ x_t,
    const float* __restrict__ z, const float* __restrict__ Wih,
    const float* __restrict__ Whh, const float* __restrict__ bih,
    const float* __restrict__ bhh)
{
  __shared__ float Wh[12288];
  __shared__ float Wi[1728];
  __shared__ float hs[4][64];
  __shared__ float gins[4][8];
  __shared__ float dtmp[256], dsc[8], dsh[8];
  int tid = threadIdx.x;
  if (blockIdx.x < 352){
    reduce_bn_(p3, 46, 1.f/11776.f, gam, bet, dsc, dsh, dtmp);
    int idx = blockIdx.x*256 + tid;                  // [0, 90112)
    int hd = idx / 45056; int rem = idx - hd*45056;
    int b = rem / 88, j = rem - b*88;
    const float* W = hd ? Wsd : Wm;
    const float* a = zg3 + (size_t)b*184;
    float accv = hd ? Bsd[j] : Bm[j];
    for (int i=0;i<184;i++){
      float x = a[i]*dsc[i&7] + dsh[i&7];
      accv += W[j*184+i]*x;
    }
    if (hd) ods[(size_t)b*88+j] = sp_(accv);
    else    odm[(size_t)b*88+j] = accv;
  } else {
    int idx = blockIdx.x - 352;                      // [0, 352)
    int a = idx >> 4, yb = idx & 15;
    int c = tid & 63, bl = tid >> 6;
    const float* Wg = Whh + (size_t)a*12288;
    for (int i=tid;i<12288;i+=256) Wh[i] = Wg[i];
    const float* Wig = Wih + (size_t)a*1536;
    for (int i=tid;i<1536;i+=256) Wi[(i/8)*9 + (i&7)] = Wig[i];
    float bi0 = bih[a*192+c], bi1 = bih[a*192+64+c], bi2 = bih[a*192+128+c];
    float bh0 = bhh[a*192+c], bh1 = bhh[a*192+64+c], bh2 = bhh[a*192+128+c];
    for (int bc=0;bc<8;bc++){
      int b = yb*32 + bc*4 + bl;
      __syncthreads();
      hs[bl][c] = h[((size_t)a*512 + b)*64 + c];
      if (c < 8) gins[bl][c] = (c<4) ? x_t[b*92 + a*4 + c] : z[b*92 + a*4 + (c-4)];
      __syncthreads();
      float g0=bi0, g1=bi1, g2=bi2;
      #pragma unroll
      for (int k=0;k<8;k++){
        float xv = gins[bl][k];
        g0 += Wi[c*9+k]*xv;
        g1 += Wi[(64+c)*9+k]*xv;
        g2 += Wi[(128+c)*9+k]*xv;
      }
      float q0=bh0, q1=bh1, q2=bh2;
      for (int kk=0;kk<64;kk++){
        int k = (kk + c) & 63;
        float hv = hs[bl][k];
        q0 += Wh[c*64+k]*hv;
        q1 += Wh[(64+c)*64+k]*hv;
        q2 += Wh[(128+c)*64+k]*hv;
      }
      float rg = sig_(g0+q0);
      float zg = sig_(g1+q1);
      float ng = tanhf(g2 + rg*q2);
      h[((size_t)a*512 + b)*64 + c] = (1.f-zg)*ng + zg*hs[bl][c];
    }
  }
}

__global__ __launch_bounds__(256) void k_final(const float* __restrict__ lklp,
                                               float* __restrict__ out){
  __shared__ float red[4];
  float s = 0.f;
  for (int i = threadIdx.x; i < 460; i += 256) s += lklp[i];
  s = wsum_(s);
  if ((threadIdx.x&63)==0) red[threadIdx.x>>6]=s;
  __syncthreads();
  if (threadIdx.x==0) out[0] = red[0]+red[1]+red[2]+red[3];
}

extern "C" void kernel_launch(void* const* d_in, const int* in_sizes, int n_in,
                              void* d_out, int out_size, void* d_ws, size_t ws_size,
                              hipStream_t stream)
{
  (void)in_sizes; (void)n_in; (void)out_size; (void)ws_size;
  const float* states=(const float*)d_in[0];
  const float* eps   =(const float*)d_in[1];
  const float *m1W1=(const float*)d_in[2],  *m1b1=(const float*)d_in[3],
              *m1W2=(const float*)d_in[4],  *m1b2=(const float*)d_in[5],
              *m1g =(const float*)d_in[6],  *m1bt=(const float*)d_in[7];
  const float *m2W1=(const float*)d_in[8],  *m2b1=(const float*)d_in[9],
              *m2W2=(const float*)d_in[10], *m2b2=(const float*)d_in[11],
              *m2g =(const float*)d_in[12], *m2bt=(const float*)d_in[13];
  const float *m3W1=(const float*)d_in[14], *m3b1=(const float*)d_in[15],
              *m3W2=(const float*)d_in[16], *m3b2=(const float*)d_in[17],
              *m3g =(const float*)d_in[18], *m3bt=(const float*)d_in[19];
  const float *emW=(const float*)d_in[20], *emB=(const float*)d_in[21];
  const float *esW=(const float*)d_in[22], *esB=(const float*)d_in[23];
  const float *pmW=(const float*)d_in[24], *pmB=(const float*)d_in[25];
  const float *psW=(const float*)d_in[26], *psB=(const float*)d_in[27];
  const float *dmW=(const float*)d_in[28], *dmB=(const float*)d_in[29];
  const float *dsW=(const float*)d_in[30], *dsB=(const float*)d_in[31];
  const float *gWih=(const float*)d_in[32], *gWhh=(const float*)d_in[33];
  const float *gbih=(const float*)d_in[34], *gbhh=(const float*)d_in[35];
  float* out = (float*)d_out;
  float* ws  = (float*)d_ws;

  // persistent (floats)
  float* g3    = ws;                 // [20][11776][8] = 1,884,160 (pre-BN3)
  float* h     = ws + 1884160;       // [22][512][64]  = 720,896
  float* zb    = ws + 2605056;       // [512][92]      = 47,104
  float* lklp  = ws + 2652160;       // 460
  float* scsh3 = ws + 2652620;       // [20][16] = 320
  float* scr   = ws + 2652940;
  // precompute view of scr
  float* p1p  = scr;                 // [20][46][16]   = 14,720
  float* naP  = scr + 14720;         // [20][512][184] = 1,884,160
  float* p2p  = scr + 1898880;       // [20][512][16]  = 163,840
  float* p3p  = scr + 2062720;       // [20][46][16]   = 14,720
  // loop view of scr (stream-ordered reuse)
  float* rawp = scr;                 // [8][4][512][92] = 1,507,328
  float* zp1  = scr + 1507328;       // [46][16]  = 736
  float* zna  = scr + 1508064;       // [512][184]= 94,208
  float* zp2  = scr + 1602272;       // [512][16] = 8,192
  float* zg3  = scr + 1610464;       // [11776][8]= 94,208
  float* zp3  = scr + 1704672;       // [46][16]  = 736
  // total ws: 2,652,940 + 2,077,440 = 4,730,380 floats = 18.9 MB

  hipMemsetAsync(h, 0, 720896*sizeof(float), stream);

  // ---- precompute gnn(y,p=0)/gnn(x,p=1), all t (g = p*10+t) ----
  k_stats1<<<dim3(46,20),256,0,stream>>>(states, m1W1, m1b1, m1W2, m1b2, p1p);
  k_gnn_edges<<<dim3(512,20),512,0,stream>>>(states, 47104L, p1p,
      m1W1, m1b1, m1W2, m1b2, m1g, m1bt,
      m2W1, m2b1, m2W2, m2b2, naP, p2p);
  k_gnn_node3<<<dim3(46,20),256,0,stream>>>(naP, p2p, m2g, m2bt,
      m3W1, m3b1, m3W2, m3b2, g3, p3p);
  k_bnred<<<20,256,0,stream>>>(p3p, 46, 1.f/11776.f, m3g, m3bt, scsh3);

  // ---- sequential scan ----
  for (int t=0;t<10;t++){
    k_heads<<<dim3(8,4,8),256,0,stream>>>(g3 + (size_t)t*94208,
        g3 + 942080 + (size_t)t*94208, scsh3, t, h, pmW, psW, emW, esW, rawp);
    k_fused<<<46,256,0,stream>>>(rawp, pmB, psB, emB, esB,
        eps + (size_t)t*47104, zb, lklp + t*46,
        m1W1+64, m1b1+16, m1W2+128, m1b2+16, zp1);
    k_gnn_edges<<<dim3(512,1),512,0,stream>>>(zb, 0L, zp1,
        m1W1+64, m1b1+16, m1W2+128, m1b2+16, m1g+16, m1bt+16,
        m2W1+288, m2b1+16, m2W2+128, m2b2+16, zna, zp2);
    k_gnn_node3<<<dim3(46,1),256,0,stream>>>(zna, zp2, m2g+16, m2bt+16,
        m3W1+160, m3b1+16, m3W2+128, m3b2+16, zg3, zp3);
    k_tail<<<704,256,0,stream>>>(zg3, zp3, m3g+16, m3bt+16,
        dmW, dmB, dsW, dsB, out + (size_t)t*45056, out + 450560 + (size_t)t*45056,
        h, states + (size_t)(t+1)*47104, zb, gWih, gWhh, gbih, gbhh);
  }
  k_final<<<1,256,0,stream>>>(lklp, out + 901120);
}

// Round 5
// 1029.837 us; speedup vs baseline: 17.5372x; 1.6753x over previous
//
#include <hip/hip_runtime.h>
#include <math.h>

// T=10 B=512 N_ALL=23 N_AGENTS=22 NH=8 E=506 RNN_H=64 Z_DIM=92 IN_H=1592
// node rows/group: 11776 ; gnn slice: 94208 floats ; split-K = 14 (slices of 114)

__device__ __forceinline__ float elu_(float x){ return x>0.f ? x : __expf(x)-1.f; }
__device__ __forceinline__ float sp_(float x){ return fmaxf(x,0.f)+log1pf(__expf(-fabsf(x))); }
__device__ __forceinline__ float sig_(float x){ return 1.f/(1.f+__expf(-x)); }
__device__ __forceinline__ float wsum_(float v){
  #pragma unroll
  for (int o=32;o;o>>=1) v += __shfl_down(v,o,64);
  return v;
}

// 256-thr block: reduce n x 16 partials -> BN scale/shift in LDS
__device__ __forceinline__ void reduce_bn_(const float* __restrict__ part, int n,
    float invN, const float* __restrict__ gam, const float* __restrict__ bet,
    float* sc, float* sh, float* tmp)
{
  int tid = threadIdx.x;
  int c = tid & 15, i0 = tid >> 4;
  float s = 0.f;
  for (int i = i0; i < n; i += 16) s += part[i*16 + c];
  tmp[i0*16 + c] = s;
  __syncthreads();
  if (tid < 16){
    float v = 0.f;
    #pragma unroll
    for (int i=0;i<16;i++) v += tmp[i*16 + tid];
    tmp[tid] = v;
  }
  __syncthreads();
  if (tid < 8){
    float m = tmp[tid]*invN;
    float var = tmp[8+tid]*invN - m*m;
    float rs = rsqrtf(var + 1e-5f);
    float s2 = rs*gam[tid];
    sc[tid] = s2; sh[tid] = bet[tid] - m*s2;
  }
  __syncthreads();
}

// 256-thr block stats: h[8]/thread -> part[16] = {sum8, sumsq8}
__device__ __forceinline__ void block_stats_(const float h[8], float* __restrict__ part,
                                             float red[4][16])
{
  int wid = threadIdx.x >> 6, lane = threadIdx.x & 63;
  #pragma unroll
  for (int j=0;j<8;j++){
    float a = wsum_(h[j]);
    float b = wsum_(h[j]*h[j]);
    if (lane==0){ red[wid][j]=a; red[wid][8+j]=b; }
  }
  __syncthreads();
  if (threadIdx.x < 16)
    part[threadIdx.x] = red[0][threadIdx.x]+red[1][threadIdx.x]
                       +red[2][threadIdx.x]+red[3][threadIdx.x];
}

// ---- MLP1 stats only (precompute; g = p*10+t) ----
__global__ __launch_bounds__(256) void k_stats1(
    const float* __restrict__ states,
    const float* __restrict__ W1b, const float* __restrict__ b1b,
    const float* __restrict__ W2b, const float* __restrict__ b2b,
    float* __restrict__ part)
{
  int g = blockIdx.y; int p = g/10; int t = g - p*10;
  const float* W1 = W1b + p*32; const float* b1 = b1b + p*8;
  const float* W2 = W2b + p*64; const float* b2 = b2b + p*8;
  int row = blockIdx.x*256 + threadIdx.x;            // [0, 11776)
  float4 x4 = *(const float4*)(states + (size_t)(t+p)*47104 + 4*(size_t)row);
  float h1[8], h2[8];
  #pragma unroll
  for (int j=0;j<8;j++){
    float a = b1[j] + W1[j*4+0]*x4.x + W1[j*4+1]*x4.y + W1[j*4+2]*x4.z + W1[j*4+3]*x4.w;
    h1[j] = elu_(a);
  }
  #pragma unroll
  for (int j=0;j<8;j++){
    float a = b2[j];
    #pragma unroll
    for (int k=0;k<8;k++) a += W2[j*8+k]*h1[k];
    h2[j] = elu_(a);
  }
  __shared__ float red[4][16];
  block_stats_(h2, part + ((size_t)g*46 + blockIdx.x)*16, red);
}

// ---- per-sample: MLP1 (recomputed) + BN1 + edge MLP (once) -> receiver sums + BN2 stats ----
__global__ __launch_bounds__(512) void k_gnn_edges(
    const float* __restrict__ src, long sstride, const float* __restrict__ p1,
    const float* __restrict__ nW1b, const float* __restrict__ nb1b,
    const float* __restrict__ nW2b, const float* __restrict__ nb2b,
    const float* __restrict__ g1b, const float* __restrict__ bt1b,
    const float* __restrict__ eW1b, const float* __restrict__ eb1b,
    const float* __restrict__ eW2b, const float* __restrict__ eb2b,
    float* __restrict__ nodeacc, float* __restrict__ p2)
{
  int g = blockIdx.y; int p = g/10; int t = g - p*10; int b = blockIdx.x;
  int tid = threadIdx.x;
  __shared__ float tmp[512];
  __shared__ float sc1[8], sh1[8];
  __shared__ float xnode[207];   // 23 x 9
  __shared__ float le[4554];     // 506 x 9
  __shared__ float accs[207];    // 23 x 9
  __shared__ float redsq[8][8];
  { // BN1 reduce over 46 partials, 512 threads
    const float* pp = p1 + (size_t)g*736;
    int c = tid & 15, i0 = tid >> 4;                 // 32 groups
    float s = 0.f;
    for (int i = i0; i < 46; i += 32) s += pp[i*16 + c];
    tmp[i0*16 + c] = s;
    __syncthreads();
    if (tid < 16){
      float v = 0.f;
      #pragma unroll
      for (int i=0;i<32;i++) v += tmp[i*16 + tid];
      tmp[tid] = v;
    }
    __syncthreads();
    if (tid < 8){
      float m = tmp[tid]*(1.f/11776.f);
      float var = tmp[8+tid]*(1.f/11776.f) - m*m;
      float rs = rsqrtf(var + 1e-5f);
      float s2 = rs*g1b[p*8+tid];
      sc1[tid] = s2; sh1[tid] = bt1b[p*8+tid] - m*s2;
    }
    __syncthreads();
  }
  if (tid < 23){ // node MLP1 + BN1
    const float* x = src + (size_t)(t+p)*sstride + (size_t)b*92 + tid*4;
    const float* W1 = nW1b + p*32; const float* b1 = nb1b + p*8;
    const float* W2 = nW2b + p*64; const float* b2 = nb2b + p*8;
    float x0=x[0], x1=x[1], x2=x[2], x3=x[3];
    float h1[8], h2[8];
    #pragma unroll
    for (int j=0;j<8;j++){
      float a = b1[j] + W1[j*4+0]*x0 + W1[j*4+1]*x1 + W1[j*4+2]*x2 + W1[j*4+3]*x3;
      h1[j] = elu_(a);
    }
    #pragma unroll
    for (int j=0;j<8;j++){
      float a = b2[j];
      #pragma unroll
      for (int k=0;k<8;k++) a += W2[j*8+k]*h1[k];
      h2[j] = elu_(a);
      xnode[tid*9+j] = h2[j]*sc1[j] + sh1[j];
    }
  }
  __syncthreads();
  float sq[8] = {0,0,0,0,0,0,0,0};
  if (tid < 506){
    int r = tid/22, jj = tid - r*22;
    int s = jj + (jj>=r ? 1 : 0);
    const float* W1 = eW1b + p*144; const float* b1 = eb1b + p*8;
    const float* W2 = eW2b + p*64;  const float* b2 = eb2b + p*8;
    float et0 = (jj==0 && r>=1 && r<=21) ? 1.f : 0.f;
    float et1 = (r==22) ? 1.f : 0.f;
    float h1[8];
    #pragma unroll
    for (int j=0;j<8;j++){
      const float* w = W1 + j*18;
      float a = b1[j] + w[16]*et0 + w[17]*et1;
      #pragma unroll
      for (int k=0;k<8;k++) a += w[k]*xnode[s*9+k];
      #pragma unroll
      for (int k=0;k<8;k++) a += w[8+k]*xnode[r*9+k];
      h1[j] = elu_(a);
    }
    #pragma unroll
    for (int j=0;j<8;j++){
      float a = b2[j];
      #pragma unroll
      for (int k=0;k<8;k++) a += W2[j*8+k]*h1[k];
      float h2 = elu_(a);
      le[tid*9+j] = h2;
      sq[j] = h2*h2;
    }
  }
  int wid = tid >> 6, lane = tid & 63;
  #pragma unroll
  for (int j=0;j<8;j++){
    float v = wsum_(sq[j]);
    if (lane==0) redsq[wid][j] = v;
  }
  __syncthreads();
  if (tid < 184){ // per-receiver pre-BN sums
    int r = tid >> 3, c = tid & 7;
    const float* lp = le + r*198 + c;
    float s = 0.f;
    #pragma unroll
    for (int jj=0;jj<22;jj++) s += lp[jj*9];
    accs[r*9+c] = s;
    nodeacc[((size_t)g*512 + b)*184 + tid] = s;
  }
  __syncthreads();
  if (tid < 16){
    int c = tid & 7;
    float s = 0.f;
    if (tid < 8){
      #pragma unroll
      for (int r=0;r<23;r++) s += accs[r*9+c];
    } else {
      #pragma unroll
      for (int w=0;w<8;w++) s += redsq[w][c];
    }
    p2[((size_t)g*512 + b)*16 + tid] = s;
  }
}

// ---- BN2 analytic + MLP3 -> pre-BN g3 + BN3 partials ----
__global__ __launch_bounds__(256) void k_gnn_node3(
    const float* __restrict__ nodeacc, const float* __restrict__ p2,
    const float* __restrict__ g2b, const float* __restrict__ bt2b,
    const float* __restrict__ W3b, const float* __restrict__ b3b,
    const float* __restrict__ W4b, const float* __restrict__ b4b,
    float* __restrict__ out, float* __restrict__ p3)
{
  int g = blockIdx.y; int p = g/10;
  __shared__ float tmp[256], sc2[8], sh2[8];
  reduce_bn_(p2 + (size_t)g*8192, 512, 1.f/259072.f, g2b+p*8, bt2b+p*8, sc2, sh2, tmp);
  int row = blockIdx.x*256 + threadIdx.x;            // [0, 11776)
  int b = row/23, r = row - b*23;
  const float inv23 = 1.f/23.f;
  const float* na = nodeacc + ((size_t)g*512 + b)*184 + r*8;
  float xk[8];
  #pragma unroll
  for (int k=0;k<8;k++) xk[k] = (na[k]*sc2[k] + 22.f*sh2[k]) * inv23;
  float nt0 = (r<22)?inv23:0.f, nt1 = (r==22)?inv23:0.f;
  const float* W3 = W3b + p*80; const float* b3 = b3b + p*8;
  const float* W4 = W4b + p*64; const float* b4 = b4b + p*8;
  float h1b[8], o[8];
  #pragma unroll
  for (int j=0;j<8;j++){
    const float* w = W3 + j*10;
    float a = b3[j] + w[8]*nt0 + w[9]*nt1;
    #pragma unroll
    for (int k=0;k<8;k++) a += w[k]*xk[k];
    h1b[j] = elu_(a);
  }
  #pragma unroll
  for (int j=0;j<8;j++){
    float a = b4[j];
    #pragma unroll
    for (int k=0;k<8;k++) a += W4[j*8+k]*h1b[k];
    o[j] = elu_(a);
    out[((size_t)g*11776 + row)*8 + j] = o[j];
  }
  __shared__ float red[4][16];
  block_stats_(o, p3 + ((size_t)g*46 + blockIdx.x)*16, red);
}

// ---- reduce n x 16 partials -> scsh[g][16] ----
__global__ __launch_bounds__(256) void k_bnred(
    const float* __restrict__ part, int n, float invN,
    const float* __restrict__ gamb, const float* __restrict__ betb,
    float* __restrict__ scsh)
{
  int g = blockIdx.x; int p = g/10;
  int tid = threadIdx.x;
  __shared__ float tmp[256];
  const float* pp = part + (size_t)g*n*16;
  int c = tid & 15, i0 = tid >> 4;
  float s = 0.f;
  for (int i = i0; i < n; i += 16) s += pp[i*16 + c];
  tmp[i0*16 + c] = s;
  __syncthreads();
  if (tid < 16){
    float v = 0.f;
    #pragma unroll
    for (int i=0;i<16;i++) v += tmp[i*16 + tid];
    tmp[tid] = v;
  }
  __syncthreads();
  if (tid < 8){
    float m = tmp[tid]*invN;
    float var = tmp[8+tid]*invN - m*m;
    float rs = rsqrtf(var + 1e-5f);
    float sc = rs*gamb[p*8+tid];
    scsh[g*16 + tid] = sc;
    scsh[g*16 + 8 + tid] = betb[p*8+tid] - m*sc;
  }
}

// ---- heads: split-K(14) tiled GEMM, BN3 applied during A staging ----
__global__ __launch_bounds__(256) void k_heads(
    const float* __restrict__ gy, const float* __restrict__ gx,
    const float* __restrict__ scsh3, int t,
    const float* __restrict__ h,
    const float* __restrict__ Wpm, const float* __restrict__ Wps,
    const float* __restrict__ Wem, const float* __restrict__ Wes,
    float* __restrict__ rawp)
{
  int head = blockIdx.y;
  const float* W  = (head==0)?Wpm:(head==1)?Wps:(head==2)?Wem:Wes;
  const float* gsel = (head<2)?gy:gx;
  int sel = (head<2) ? t : 10+t;
  __shared__ float s3[16];
  __shared__ float As[16][68];
  __shared__ float Ws[16][100];
  int tid = threadIdx.x;
  if (tid < 16) s3[tid] = scsh3[sel*16 + tid];
  int b0 = blockIdx.x*64;
  int kbeg = blockIdx.z*114;
  int kend = kbeg+114; if (kend > 1592) kend = 1592;
  int tb = tid & 15, tj = tid >> 4;
  float acc[4][6];
  #pragma unroll
  for (int u=0;u<4;u++)
    #pragma unroll
    for (int vv=0;vv<6;vv++) acc[u][vv]=0.f;
  __syncthreads();
  for (int k0=kbeg; k0<kend; k0+=16){
    #pragma unroll
    for (int l=0;l<4;l++){
      int lin = tid + 256*l;
      int kk = lin & 15, bl = lin >> 4;
      int i = k0 + kk;
      float v = 0.f;
      if (i < kend){
        int bb = b0 + bl;
        if (i < 184){ int c = i&7; v = gsel[bb*184 + i]*s3[c] + s3[8+c]; }
        else { int i2 = i - 184; v = h[(size_t)(i2>>6)*32768 + bb*64 + (i2&63)]; }
      }
      As[kk][bl] = v;
    }
    #pragma unroll
    for (int l=0;l<6;l++){
      int lin = tid + 256*l;
      int kk = lin & 15, jl = lin >> 4;
      int i = k0 + kk;
      float v = 0.f;
      if (i < kend && jl < 92) v = W[jl*1592 + i];
      Ws[kk][jl] = v;
    }
    __syncthreads();
    #pragma unroll
    for (int kk=0;kk<16;kk++){
      float4 a4 = *(const float4*)&As[kk][tb*4];
      float av[4] = {a4.x,a4.y,a4.z,a4.w};
      float2 w01 = *(const float2*)&Ws[kk][tj*6];
      float2 w23 = *(const float2*)&Ws[kk][tj*6+2];
      float2 w45 = *(const float2*)&Ws[kk][tj*6+4];
      float wv[6] = {w01.x,w01.y,w23.x,w23.y,w45.x,w45.y};
      #pragma unroll
      for (int u=0;u<4;u++)
        #pragma unroll
        for (int vv=0;vv<6;vv++) acc[u][vv] += av[u]*wv[vv];
    }
    __syncthreads();
  }
  float* dst = rawp + (size_t)blockIdx.z*188416 + (size_t)head*47104;
  #pragma unroll
  for (int u=0;u<4;u++){
    int bb = b0 + tb*4 + u;
    #pragma unroll
    for (int vv=0;vv<6;vv++){
      int j = tj*6 + vv;
      if (j < 92) dst[bb*92 + j] = acc[u][vv];
    }
  }
}

// ---- fused: split-K combine + bias + sample + KLD + MLP1(set2) stats ----
__global__ __launch_bounds__(256) void k_fused(
    const float* __restrict__ rawp,
    const float* __restrict__ bpm, const float* __restrict__ bps,
    const float* __restrict__ bem, const float* __restrict__ bes,
    const float* __restrict__ eps_t, float* __restrict__ z,
    float* __restrict__ lklp,
    const float* __restrict__ W1, const float* __restrict__ b1,
    const float* __restrict__ W2, const float* __restrict__ b2,
    float* __restrict__ part)
{
  int tid = threadIdx.x;
  int row = blockIdx.x*256 + tid;                    // [0, 11776)
  int bb = row/23, n = row - bb*23;
  (void)bb;
  float pm[4]={0,0,0,0}, ps[4]={0,0,0,0}, em[4]={0,0,0,0}, es[4]={0,0,0,0};
  const float* rp = rawp + 4*(size_t)row;
  #pragma unroll
  for (int zz=0;zz<14;zz++){
    const float* q = rp + (size_t)zz*188416;
    float4 a = *(const float4*)(q);
    float4 bq = *(const float4*)(q + 47104);
    float4 c = *(const float4*)(q + 94208);
    float4 d = *(const float4*)(q + 141312);
    pm[0]+=a.x; pm[1]+=a.y; pm[2]+=a.z; pm[3]+=a.w;
    ps[0]+=bq.x; ps[1]+=bq.y; ps[2]+=bq.z; ps[3]+=bq.w;
    em[0]+=c.x; em[1]+=c.y; em[2]+=c.z; em[3]+=c.w;
    es[0]+=d.x; es[1]+=d.y; es[2]+=d.z; es[3]+=d.w;
  }
  int j0 = 4*n;
  float4 e4 = *(const float4*)(eps_t + 4*(size_t)row);
  float ev[4] = {e4.x, e4.y, e4.z, e4.w};
  float zv[4]; float kl = 0.f;
  #pragma unroll
  for (int q=0;q<4;q++){
    float PM = pm[q] + bpm[j0+q];
    float PS = sp_(ps[q] + bps[j0+q]);
    float EM = em[q] + bem[j0+q];
    float ES = sp_(es[q] + bes[j0+q]);
    zv[q] = EM + ES*ev[q];
    float d = EM - PM;
    kl += 0.5f*(2.f*logf(PS/ES) + (ES*ES + d*d)/(PS*PS) - 1.f);
  }
  float4 zq; zq.x=zv[0]; zq.y=zv[1]; zq.z=zv[2]; zq.w=zv[3];
  *(float4*)(z + 4*(size_t)row) = zq;
  __shared__ float redk[4];
  float ks = wsum_(kl);
  if ((tid&63)==0) redk[tid>>6] = ks;
  __syncthreads();
  if (tid==0) lklp[blockIdx.x] = redk[0]+redk[1]+redk[2]+redk[3];
  float h1[8], h2[8];
  #pragma unroll
  for (int j=0;j<8;j++){
    float a = b1[j] + W1[j*4+0]*zv[0] + W1[j*4+1]*zv[1] + W1[j*4+2]*zv[2] + W1[j*4+3]*zv[3];
    h1[j] = elu_(a);
  }
  #pragma unroll
  for (int j=0;j<8;j++){
    float a = b2[j];
    #pragma unroll
    for (int k=0;k<8;k++) a += W2[j*8+k]*h1[k];
    h2[j] = elu_(a);
  }
  __shared__ float red[4][16];
  block_stats_(h2, part + (size_t)blockIdx.x*16, red);
}

// ---- tail: blocks [0,352) dec (BN3 inline, float4), [352,704) GRU (conflict-free) ----
// GRU LDS: WhT[64][193] transposed weights (stride 193 == 1 mod 32: conflict-free
// staging writes AND reads), hs[64][36] k-major samples (b128 broadcast reads),
// gins[8][36]. Wi kept in registers. 4 samples/thread, 2 passes.
__global__ __launch_bounds__(256) void k_tail(
    const float* __restrict__ zg3, const float* __restrict__ p3,
    const float* __restrict__ gam, const float* __restrict__ bet,
    const float* __restrict__ Wm, const float* __restrict__ Bm,
    const float* __restrict__ Wsd, const float* __restrict__ Bsd,
    float* __restrict__ odm, float* __restrict__ ods,
    float* __restrict__ h, const float* __restrict__ x_t,
    const float* __restrict__ z, const float* __restrict__ Wih,
    const float* __restrict__ Whh, const float* __restrict__ bih,
    const float* __restrict__ bhh)
{
  __shared__ float smem[14944];  // 58.4 KB union
  int tid = threadIdx.x;
  if (blockIdx.x < 352){
    float* dtmp = smem; float* dsc = smem + 256; float* dsh = smem + 264;
    reduce_bn_(p3, 46, 1.f/11776.f, gam, bet, dsc, dsh, dtmp);
    float4 s0 = {dsc[0],dsc[1],dsc[2],dsc[3]};
    float4 s1 = {dsc[4],dsc[5],dsc[6],dsc[7]};
    float4 t0 = {dsh[0],dsh[1],dsh[2],dsh[3]};
    float4 t1 = {dsh[4],dsh[5],dsh[6],dsh[7]};
    int idx = blockIdx.x*256 + tid;                  // [0, 90112)
    int hd = idx / 45056; int rem = idx - hd*45056;
    int b = rem / 88, j = rem - b*88;
    const float* W = hd ? Wsd : Wm;
    const float4* a4 = (const float4*)(zg3 + (size_t)b*184);
    const float4* w4 = (const float4*)(W + (size_t)j*184);
    float accv = hd ? Bsd[j] : Bm[j];
    #pragma unroll 2
    for (int i4=0;i4<46;i4++){
      float4 x = a4[i4]; float4 w = w4[i4];
      float4 sc = (i4&1)? s1 : s0; float4 sh = (i4&1)? t1 : t0;
      accv += w.x*(x.x*sc.x+sh.x) + w.y*(x.y*sc.y+sh.y)
            + w.z*(x.z*sc.z+sh.z) + w.w*(x.w*sc.w+sh.w);
    }
    if (hd) ods[(size_t)b*88+j] = sp_(accv);
    else    odm[(size_t)b*88+j] = accv;
  } else {
    float* WhT  = smem;           // 64*193 = 12352
    float* hs   = smem + 12352;   // 64*36  = 2304
    float* gins = smem + 14656;   // 8*36   = 288
    int idx = blockIdx.x - 352;                      // [0, 352)
    int a = idx >> 4, yb = idx & 15;
    int b0 = yb*32;
    int c = tid & 63, sq = tid >> 6;
    // stage WhT[k][row] = Whh[a][row][k] ; lanes walk k -> write stride 193 (==1 mod 32)
    const float* Wg = Whh + (size_t)a*12288;
    for (int e = tid; e < 12288; e += 256) WhT[(e&63)*193 + (e>>6)] = Wg[e];
    // stage hs[k][b] = h[a][b0+b][k]
    const float* hp_g = h + (size_t)a*32768 + (size_t)b0*64;
    for (int e = tid; e < 2048; e += 256) hs[(e&63)*36 + (e>>6)] = hp_g[e];
    // stage gins[k][s]
    { int s = tid >> 3, k = tid & 7;
      float v = (k<4) ? x_t[(size_t)(b0+s)*92 + a*4 + k]
                      : z[(size_t)(b0+s)*92 + a*4 + (k-4)];
      gins[k*36 + s] = v; }
    // Wi rows to registers
    float wi0[8], wi1[8], wi2[8];
    const float* Wig = Wih + (size_t)a*1536;
    #pragma unroll
    for (int k=0;k<8;k++){
      wi0[k] = Wig[c*8+k]; wi1[k] = Wig[(64+c)*8+k]; wi2[k] = Wig[(128+c)*8+k];
    }
    float bi0 = bih[a*192+c], bi1 = bih[a*192+64+c], bi2 = bih[a*192+128+c];
    float bh0 = bhh[a*192+c], bh1 = bhh[a*192+64+c], bh2 = bhh[a*192+128+c];
    __syncthreads();
    #pragma unroll
    for (int ps=0; ps<2; ps++){
      int s0 = ps*16 + sq*4;
      float q0[4], q1[4], q2[4];
      #pragma unroll
      for (int i=0;i<4;i++){ q0[i]=bh0; q1[i]=bh1; q2[i]=bh2; }
      for (int k=0;k<64;k++){
        float w0 = WhT[k*193 + c];
        float w1 = WhT[k*193 + 64 + c];
        float w2 = WhT[k*193 + 128 + c];
        float4 hv = *(const float4*)&hs[k*36 + s0];
        float hvv[4] = {hv.x,hv.y,hv.z,hv.w};
        #pragma unroll
        for (int i=0;i<4;i++){ q0[i]+=w0*hvv[i]; q1[i]+=w1*hvv[i]; q2[i]+=w2*hvv[i]; }
      }
      float g0[4], g1[4], g2[4];
      #pragma unroll
      for (int i=0;i<4;i++){ g0[i]=bi0; g1[i]=bi1; g2[i]=bi2; }
      #pragma unroll
      for (int k=0;k<8;k++){
        float4 gv = *(const float4*)&gins[k*36 + s0];
        float gvv[4] = {gv.x,gv.y,gv.z,gv.w};
        #pragma unroll
        for (int i=0;i<4;i++){ g0[i]+=wi0[k]*gvv[i]; g1[i]+=wi1[k]*gvv[i]; g2[i]+=wi2[k]*gvv[i]; }
      }
      float4 hp = *(const float4*)&hs[c*36 + s0];
      float hpv[4] = {hp.x,hp.y,hp.z,hp.w};
      #pragma unroll
      for (int i=0;i<4;i++){
        float rg = sig_(g0[i]+q0[i]);
        float zg = sig_(g1[i]+q1[i]);
        float ng = tanhf(g2[i] + rg*q2[i]);
        h[(size_t)a*32768 + (size_t)(b0+s0+i)*64 + c] = (1.f-zg)*ng + zg*hpv[i];
      }
    }
  }
}

__global__ __launch_bounds__(256) void k_final(const float* __restrict__ lklp,
                                               float* __restrict__ out){
  __shared__ float red[4];
  float s = 0.f;
  for (int i = threadIdx.x; i < 460; i += 256) s += lklp[i];
  s = wsum_(s);
  if ((threadIdx.x&63)==0) red[threadIdx.x>>6]=s;
  __syncthreads();
  if (threadIdx.x==0) out[0] = red[0]+red[1]+red[2]+red[3];
}

extern "C" void kernel_launch(void* const* d_in, const int* in_sizes, int n_in,
                              void* d_out, int out_size, void* d_ws, size_t ws_size,
                              hipStream_t stream)
{
  (void)in_sizes; (void)n_in; (void)out_size; (void)ws_size;
  const float* states=(const float*)d_in[0];
  const float* eps   =(const float*)d_in[1];
  const float *m1W1=(const float*)d_in[2],  *m1b1=(const float*)d_in[3],
              *m1W2=(const float*)d_in[4],  *m1b2=(const float*)d_in[5],
              *m1g =(const float*)d_in[6],  *m1bt=(const float*)d_in[7];
  const float *m2W1=(const float*)d_in[8],  *m2b1=(const float*)d_in[9],
              *m2W2=(const float*)d_in[10], *m2b2=(const float*)d_in[11],
              *m2g =(const float*)d_in[12], *m2bt=(const float*)d_in[13];
  const float *m3W1=(const float*)d_in[14], *m3b1=(const float*)d_in[15],
              *m3W2=(const float*)d_in[16], *m3b2=(const float*)d_in[17],
              *m3g =(const float*)d_in[18], *m3bt=(const float*)d_in[19];
  const float *emW=(const float*)d_in[20], *emB=(const float*)d_in[21];
  const float *esW=(const float*)d_in[22], *esB=(const float*)d_in[23];
  const float *pmW=(const float*)d_in[24], *pmB=(const float*)d_in[25];
  const float *psW=(const float*)d_in[26], *psB=(const float*)d_in[27];
  const float *dmW=(const float*)d_in[28], *dmB=(const float*)d_in[29];
  const float *dsW=(const float*)d_in[30], *dsB=(const float*)d_in[31];
  const float *gWih=(const float*)d_in[32], *gWhh=(const float*)d_in[33];
  const float *gbih=(const float*)d_in[34], *gbhh=(const float*)d_in[35];
  float* out = (float*)d_out;
  float* ws  = (float*)d_ws;

  // persistent (floats)
  float* g3    = ws;                 // [20][11776][8] = 1,884,160 (pre-BN3)
  float* h     = ws + 1884160;       // [22][512][64]  = 720,896
  float* zb    = ws + 2605056;       // [512][92]      = 47,104
  float* lklp  = ws + 2652160;       // 460
  float* scsh3 = ws + 2652620;       // [20][16] = 320
  float* scr   = ws + 2652940;
  // precompute view of scr
  float* p1p  = scr;                 // [20][46][16]   = 14,720
  float* naP  = scr + 14720;         // [20][512][184] = 1,884,160
  float* p2p  = scr + 1898880;       // [20][512][16]  = 163,840
  float* p3p  = scr + 2062720;       // [20][46][16]   = 14,720
  // loop view of scr (stream-ordered reuse; zna/zg3 alias dead rawp region)
  float* rawp = scr;                 // [14][4][512][92] = 2,637,824
  float* zp1  = scr + 2637824;       // [46][16]  = 736  (outside rawp: written while rawp read)
  float* zna  = scr;                 // [512][184]= 94,208 (rawp dead after k_fused)
  float* zp2  = scr + 94208;         // [512][16] = 8,192
  float* zg3  = scr + 102400;        // [11776][8]= 94,208
  float* zp3  = scr + 196608;        // [46][16]  = 736
  // total ws: 2,652,940 + 2,638,560 = 5,291,500 floats = 21.2 MB (< proven 22.5 MB)

  hipMemsetAsync(h, 0, 720896*sizeof(float), stream);

  // ---- precompute gnn(y,p=0)/gnn(x,p=1), all t (g = p*10+t) ----
  k_stats1<<<dim3(46,20),256,0,stream>>>(states, m1W1, m1b1, m1W2, m1b2, p1p);
  k_gnn_edges<<<dim3(512,20),512,0,stream>>>(states, 47104L, p1p,
      m1W1, m1b1, m1W2, m1b2, m1g, m1bt,
      m2W1, m2b1, m2W2, m2b2, naP, p2p);
  k_gnn_node3<<<dim3(46,20),256,0,stream>>>(naP, p2p, m2g, m2bt,
      m3W1, m3b1, m3W2, m3b2, g3, p3p);
  k_bnred<<<20,256,0,stream>>>(p3p, 46, 1.f/11776.f, m3g, m3bt, scsh3);

  // ---- sequential scan ----
  for (int t=0;t<10;t++){
    k_heads<<<dim3(8,4,14),256,0,stream>>>(g3 + (size_t)t*94208,
        g3 + 942080 + (size_t)t*94208, scsh3, t, h, pmW, psW, emW, esW, rawp);
    k_fused<<<46,256,0,stream>>>(rawp, pmB, psB, emB, esB,
        eps + (size_t)t*47104, zb, lklp + t*46,
        m1W1+64, m1b1+16, m1W2+128, m1b2+16, zp1);
    k_gnn_edges<<<dim3(512,1),512,0,stream>>>(zb, 0L, zp1,
        m1W1+64, m1b1+16, m1W2+128, m1b2+16, m1g+16, m1bt+16,
        m2W1+288, m2b1+16, m2W2+128, m2b2+16, zna, zp2);
    k_gnn_node3<<<dim3(46,1),256,0,stream>>>(zna, zp2, m2g+16, m2bt+16,
        m3W1+160, m3b1+16, m3W2+128, m3b2+16, zg3, zp3);
    k_tail<<<704,256,0,stream>>>(zg3, zp3, m3g+16, m3bt+16,
        dmW, dmB, dsW, dsB, out + (size_t)t*45056, out + 450560 + (size_t)t*45056,
        h, states + (size_t)(t+1)*47104, zb, gWih, gWhh, gbih, gbhh);
  }
  k_final<<<1,256,0,stream>>>(lklp, out + 901120);
}

// Round 6
// 852.437 us; speedup vs baseline: 21.1869x; 1.2081x over previous
//
#include <hip/hip_runtime.h>
#include <math.h>

// T=10 B=512 N_ALL=23 N_AGENTS=22 NH=8 E=506 RNN_H=64 Z_DIM=92 IN_H=1592
// Pipeline: K1(t)=heads(t)+edges(t-1) | K2(t)=fused(t)+node3(t-1) | K3(t)=gru(t)+dec(t-1)

__device__ __forceinline__ float elu_(float x){ return x>0.f ? x : __expf(x)-1.f; }
__device__ __forceinline__ float sp_(float x){ return fmaxf(x,0.f)+log1pf(__expf(-fabsf(x))); }
__device__ __forceinline__ float sig_(float x){ return 1.f/(1.f+__expf(-x)); }
__device__ __forceinline__ float wsum_(float v){
  #pragma unroll
  for (int o=32;o;o>>=1) v += __shfl_down(v,o,64);
  return v;
}

// 256-thr block: reduce n x 16 partials -> BN scale/shift in LDS
__device__ __forceinline__ void reduce_bn_(const float* __restrict__ part, int n,
    float invN, const float* __restrict__ gam, const float* __restrict__ bet,
    float* sc, float* sh, float* tmp)
{
  int tid = threadIdx.x;
  int c = tid & 15, i0 = tid >> 4;
  float s = 0.f;
  for (int i = i0; i < n; i += 16) s += part[i*16 + c];
  tmp[i0*16 + c] = s;
  __syncthreads();
  if (tid < 16){
    float v = 0.f;
    #pragma unroll
    for (int i=0;i<16;i++) v += tmp[i*16 + tid];
    tmp[tid] = v;
  }
  __syncthreads();
  if (tid < 8){
    float m = tmp[tid]*invN;
    float var = tmp[8+tid]*invN - m*m;
    float rs = rsqrtf(var + 1e-5f);
    float s2 = rs*gam[tid];
    sc[tid] = s2; sh[tid] = bet[tid] - m*s2;
  }
  __syncthreads();
}

// 256-thr block stats: h[8]/thread -> part[16] = {sum8, sumsq8}
__device__ __forceinline__ void block_stats_(const float h[8], float* __restrict__ part,
                                             float red[4][16])
{
  int wid = threadIdx.x >> 6, lane = threadIdx.x & 63;
  #pragma unroll
  for (int j=0;j<8;j++){
    float a = wsum_(h[j]);
    float b = wsum_(h[j]*h[j]);
    if (lane==0){ red[wid][j]=a; red[wid][8+j]=b; }
  }
  __syncthreads();
  if (threadIdx.x < 16)
    part[threadIdx.x] = red[0][threadIdx.x]+red[1][threadIdx.x]
                       +red[2][threadIdx.x]+red[3][threadIdx.x];
}

// ================= device building blocks =================

// edges: per-sample block (256 thr): BN1-reduce, node MLP1+BN1, edge MLP once,
// receiver pre-BN sums + BN2 stats partials. smem: 5274 floats.
__device__ __forceinline__ void dev_edges(
    float* smem, int b, int g, int p, int t,
    const float* __restrict__ src, long sstride, const float* __restrict__ p1,
    const float* __restrict__ nW1b, const float* __restrict__ nb1b,
    const float* __restrict__ nW2b, const float* __restrict__ nb2b,
    const float* __restrict__ g1b, const float* __restrict__ bt1b,
    const float* __restrict__ eW1b, const float* __restrict__ eb1b,
    const float* __restrict__ eW2b, const float* __restrict__ eb2b,
    float* __restrict__ nodeacc, float* __restrict__ p2)
{
  int tid = threadIdx.x;
  float* tmp   = smem;        // 256
  float* sc1   = smem+256;    // 8
  float* sh1   = smem+264;    // 8
  float* xnode = smem+272;    // 207
  float* accs  = smem+480;    // 207
  float* redsq = smem+688;    // 32
  float* le    = smem+720;    // 4554
  {
    const float* pp = p1 + (size_t)g*736;
    int c = tid & 15, i0 = tid >> 4;
    float s = 0.f;
    for (int i=i0;i<46;i+=16) s += pp[i*16+c];
    tmp[i0*16+c] = s;
    __syncthreads();
    if (tid<16){
      float v=0.f;
      #pragma unroll
      for (int i=0;i<16;i++) v += tmp[i*16+tid];
      tmp[tid]=v;
    }
    __syncthreads();
    if (tid<8){
      float m = tmp[tid]*(1.f/11776.f);
      float var = tmp[8+tid]*(1.f/11776.f) - m*m;
      float rs = rsqrtf(var+1e-5f);
      float s2 = rs*g1b[p*8+tid];
      sc1[tid]=s2; sh1[tid]=bt1b[p*8+tid]-m*s2;
    }
    __syncthreads();
  }
  if (tid<23){
    const float* x = src + (size_t)(t+p)*sstride + (size_t)b*92 + tid*4;
    const float* W1 = nW1b+p*32; const float* b1 = nb1b+p*8;
    const float* W2 = nW2b+p*64; const float* b2 = nb2b+p*8;
    float x0=x[0],x1=x[1],x2=x[2],x3=x[3];
    float h1[8];
    #pragma unroll
    for (int j=0;j<8;j++)
      h1[j]=elu_(b1[j]+W1[j*4]*x0+W1[j*4+1]*x1+W1[j*4+2]*x2+W1[j*4+3]*x3);
    #pragma unroll
    for (int j=0;j<8;j++){
      float a=b2[j];
      #pragma unroll
      for (int k=0;k<8;k++) a+=W2[j*8+k]*h1[k];
      xnode[tid*9+j]=elu_(a)*sc1[j]+sh1[j];
    }
  }
  __syncthreads();
  float sq[8]={0,0,0,0,0,0,0,0};
  {
    const float* W1 = eW1b+p*144; const float* b1 = eb1b+p*8;
    const float* W2 = eW2b+p*64;  const float* b2 = eb2b+p*8;
    for (int e=tid; e<506; e+=256){
      int r=e/22, jj=e-r*22;
      int s=jj+(jj>=r?1:0);
      float et0=(jj==0 && r>=1 && r<=21)?1.f:0.f;
      float et1=(r==22)?1.f:0.f;
      float xs[8], xr[8];
      #pragma unroll
      for (int k=0;k<8;k++){ xs[k]=xnode[s*9+k]; xr[k]=xnode[r*9+k]; }
      float h1[8];
      #pragma unroll
      for (int j=0;j<8;j++){
        const float* w=W1+j*18;
        float a=b1[j]+w[16]*et0+w[17]*et1;
        #pragma unroll
        for (int k=0;k<8;k++) a+=w[k]*xs[k];
        #pragma unroll
        for (int k=0;k<8;k++) a+=w[8+k]*xr[k];
        h1[j]=elu_(a);
      }
      #pragma unroll
      for (int j=0;j<8;j++){
        float a=b2[j];
        #pragma unroll
        for (int k=0;k<8;k++) a+=W2[j*8+k]*h1[k];
        float h2=elu_(a);
        le[e*9+j]=h2;
        sq[j]+=h2*h2;
      }
    }
  }
  int wid=tid>>6, lane=tid&63;
  #pragma unroll
  for (int j=0;j<8;j++){
    float v=wsum_(sq[j]);
    if (lane==0) redsq[wid*8+j]=v;
  }
  __syncthreads();
  if (tid<184){
    int r=tid>>3, c=tid&7;
    const float* lp = le + r*198 + c;
    float s=0.f;
    #pragma unroll
    for (int jj=0;jj<22;jj++) s+=lp[jj*9];
    accs[r*9+c]=s;
    nodeacc[((size_t)g*512+b)*184+tid]=s;
  }
  __syncthreads();
  if (tid<16){
    int c=tid&7;
    float s=0.f;
    if (tid<8){
      #pragma unroll
      for (int r=0;r<23;r++) s+=accs[r*9+c];
    } else {
      #pragma unroll
      for (int w=0;w<4;w++) s+=redsq[w*8+c];
    }
    p2[((size_t)g*512+b)*16+tid]=s;
  }
}

// node3: BN2 analytic + MLP3 -> pre-BN g3 rows + BN3 partials
__device__ __forceinline__ void dev_node3(
    int bi, int g, int p,
    const float* __restrict__ nodeacc, const float* __restrict__ p2,
    const float* __restrict__ g2b, const float* __restrict__ bt2b,
    const float* __restrict__ W3b, const float* __restrict__ b3b,
    const float* __restrict__ W4b, const float* __restrict__ b4b,
    float* __restrict__ out, float* __restrict__ p3)
{
  __shared__ float tmp[256], sc2[8], sh2[8];
  __shared__ float red[4][16];
  reduce_bn_(p2 + (size_t)g*8192, 512, 1.f/259072.f, g2b+p*8, bt2b+p*8, sc2, sh2, tmp);
  int row = bi*256 + threadIdx.x;                    // [0, 11776)
  int b = row/23, r = row - b*23;
  const float inv23 = 1.f/23.f;
  const float* na = nodeacc + ((size_t)g*512 + b)*184 + r*8;
  float xk[8];
  #pragma unroll
  for (int k=0;k<8;k++) xk[k] = (na[k]*sc2[k] + 22.f*sh2[k]) * inv23;
  float nt0 = (r<22)?inv23:0.f, nt1 = (r==22)?inv23:0.f;
  const float* W3 = W3b + p*80; const float* b3 = b3b + p*8;
  const float* W4 = W4b + p*64; const float* b4 = b4b + p*8;
  float h1b[8], o[8];
  #pragma unroll
  for (int j=0;j<8;j++){
    const float* w = W3 + j*10;
    float a = b3[j] + w[8]*nt0 + w[9]*nt1;
    #pragma unroll
    for (int k=0;k<8;k++) a += w[k]*xk[k];
    h1b[j] = elu_(a);
  }
  #pragma unroll
  for (int j=0;j<8;j++){
    float a = b4[j];
    #pragma unroll
    for (int k=0;k<8;k++) a += W4[j*8+k]*h1b[k];
    o[j] = elu_(a);
    out[((size_t)g*11776 + row)*8 + j] = o[j];
  }
  block_stats_(o, p3 + ((size_t)g*46 + bi)*16, red);
}

// heads: split-K(14) tiled GEMM tile, BN3 applied in A staging. smem carve 2704 fl.
__device__ __forceinline__ void dev_heads(
    float* smem, int idx, int t,
    const float* __restrict__ gy, const float* __restrict__ gx,
    const float* __restrict__ scsh3, const float* __restrict__ h,
    const float* __restrict__ Wpm, const float* __restrict__ Wps,
    const float* __restrict__ Wem, const float* __restrict__ Wes,
    float* __restrict__ rawp)
{
  int bt = idx & 7, head = (idx>>3)&3, kz = idx>>5;
  const float* W  = (head==0)?Wpm:(head==1)?Wps:(head==2)?Wem:Wes;
  const float* gsel = (head<2)?gy:gx;
  int sel = (head<2) ? t : 10+t;
  float* s3 = smem;                                  // 16
  float (*As)[68]  = (float(*)[68])(smem+16);        // 1088
  float (*Ws)[100] = (float(*)[100])(smem+1104);     // 1600
  int tid = threadIdx.x;
  if (tid < 16) s3[tid] = scsh3[sel*16 + tid];
  int b0 = bt*64;
  int kbeg = kz*114;
  int kend = kbeg+114; if (kend > 1592) kend = 1592;
  int tb = tid & 15, tj = tid >> 4;
  float acc[4][6];
  #pragma unroll
  for (int u=0;u<4;u++)
    #pragma unroll
    for (int vv=0;vv<6;vv++) acc[u][vv]=0.f;
  __syncthreads();
  for (int k0=kbeg; k0<kend; k0+=16){
    #pragma unroll
    for (int l=0;l<4;l++){
      int lin = tid + 256*l;
      int kk = lin & 15, bl = lin >> 4;
      int i = k0 + kk;
      float v = 0.f;
      if (i < kend){
        int bb = b0 + bl;
        if (i < 184){ int c = i&7; v = gsel[bb*184 + i]*s3[c] + s3[8+c]; }
        else { int i2 = i - 184; v = h[(size_t)(i2>>6)*32768 + bb*64 + (i2&63)]; }
      }
      As[kk][bl] = v;
    }
    #pragma unroll
    for (int l=0;l<6;l++){
      int lin = tid + 256*l;
      int kk = lin & 15, jl = lin >> 4;
      int i = k0 + kk;
      float v = 0.f;
      if (i < kend && jl < 92) v = W[jl*1592 + i];
      Ws[kk][jl] = v;
    }
    __syncthreads();
    #pragma unroll
    for (int kk=0;kk<16;kk++){
      float4 a4 = *(const float4*)&As[kk][tb*4];
      float av[4] = {a4.x,a4.y,a4.z,a4.w};
      float2 w01 = *(const float2*)&Ws[kk][tj*6];
      float2 w23 = *(const float2*)&Ws[kk][tj*6+2];
      float2 w45 = *(const float2*)&Ws[kk][tj*6+4];
      float wv[6] = {w01.x,w01.y,w23.x,w23.y,w45.x,w45.y};
      #pragma unroll
      for (int u=0;u<4;u++)
        #pragma unroll
        for (int vv=0;vv<6;vv++) acc[u][vv] += av[u]*wv[vv];
    }
    __syncthreads();
  }
  float* dst = rawp + (size_t)kz*188416 + (size_t)head*47104;
  #pragma unroll
  for (int u=0;u<4;u++){
    int bb = b0 + tb*4 + u;
    #pragma unroll
    for (int vv=0;vv<6;vv++){
      int j = tj*6 + vv;
      if (j < 92) dst[bb*92 + j] = acc[u][vv];
    }
  }
}

// fused: split-K combine + bias + sample + KLD + MLP1(set2) stats
__device__ __forceinline__ void dev_fused(
    int bi,
    const float* __restrict__ rawp,
    const float* __restrict__ bpm, const float* __restrict__ bps,
    const float* __restrict__ bem, const float* __restrict__ bes,
    const float* __restrict__ eps_t, float* __restrict__ z,
    float* __restrict__ lklp,
    const float* __restrict__ W1, const float* __restrict__ b1,
    const float* __restrict__ W2, const float* __restrict__ b2,
    float* __restrict__ part)
{
  __shared__ float redk[4];
  __shared__ float red[4][16];
  int tid = threadIdx.x;
  int row = bi*256 + tid;                            // [0, 11776)
  int bb = row/23, n = row - bb*23;
  (void)bb;
  float pm[4]={0,0,0,0}, ps[4]={0,0,0,0}, em[4]={0,0,0,0}, es[4]={0,0,0,0};
  const float* rp = rawp + 4*(size_t)row;
  #pragma unroll
  for (int zz=0;zz<14;zz++){
    const float* q = rp + (size_t)zz*188416;
    float4 a = *(const float4*)(q);
    float4 bq = *(const float4*)(q + 47104);
    float4 c = *(const float4*)(q + 94208);
    float4 d = *(const float4*)(q + 141312);
    pm[0]+=a.x; pm[1]+=a.y; pm[2]+=a.z; pm[3]+=a.w;
    ps[0]+=bq.x; ps[1]+=bq.y; ps[2]+=bq.z; ps[3]+=bq.w;
    em[0]+=c.x; em[1]+=c.y; em[2]+=c.z; em[3]+=c.w;
    es[0]+=d.x; es[1]+=d.y; es[2]+=d.z; es[3]+=d.w;
  }
  int j0 = 4*n;
  float4 e4 = *(const float4*)(eps_t + 4*(size_t)row);
  float ev[4] = {e4.x, e4.y, e4.z, e4.w};
  float zv[4]; float kl = 0.f;
  #pragma unroll
  for (int q=0;q<4;q++){
    float PM = pm[q] + bpm[j0+q];
    float PS = sp_(ps[q] + bps[j0+q]);
    float EM = em[q] + bem[j0+q];
    float ES = sp_(es[q] + bes[j0+q]);
    zv[q] = EM + ES*ev[q];
    float d = EM - PM;
    kl += 0.5f*(2.f*logf(PS/ES) + (ES*ES + d*d)/(PS*PS) - 1.f);
  }
  float4 zq; zq.x=zv[0]; zq.y=zv[1]; zq.z=zv[2]; zq.w=zv[3];
  *(float4*)(z + 4*(size_t)row) = zq;
  float ks = wsum_(kl);
  if ((tid&63)==0) redk[tid>>6] = ks;
  __syncthreads();
  if (tid==0) lklp[bi] = redk[0]+redk[1]+redk[2]+redk[3];
  float h1[8], h2[8];
  #pragma unroll
  for (int j=0;j<8;j++){
    float a = b1[j] + W1[j*4+0]*zv[0] + W1[j*4+1]*zv[1] + W1[j*4+2]*zv[2] + W1[j*4+3]*zv[3];
    h1[j] = elu_(a);
  }
  #pragma unroll
  for (int j=0;j<8;j++){
    float a = b2[j];
    #pragma unroll
    for (int k=0;k<8;k++) a += W2[j*8+k]*h1[k];
    h2[j] = elu_(a);
  }
  block_stats_(h2, part + (size_t)bi*16, red);
}

// dec unit (256 thr): BN3 inline via partial reduce, float4 GEMV
__device__ __forceinline__ void dev_dec(
    float* smem, int bi,
    const float* __restrict__ zg3, const float* __restrict__ p3,
    const float* __restrict__ gam, const float* __restrict__ bet,
    const float* __restrict__ Wm, const float* __restrict__ Bm,
    const float* __restrict__ Wsd, const float* __restrict__ Bsd,
    float* __restrict__ odm, float* __restrict__ ods)
{
  int tid = threadIdx.x;
  float* dtmp = smem; float* dsc = smem + 256; float* dsh = smem + 264;
  reduce_bn_(p3, 46, 1.f/11776.f, gam, bet, dsc, dsh, dtmp);
  float4 s0 = {dsc[0],dsc[1],dsc[2],dsc[3]};
  float4 s1 = {dsc[4],dsc[5],dsc[6],dsc[7]};
  float4 t0 = {dsh[0],dsh[1],dsh[2],dsh[3]};
  float4 t1 = {dsh[4],dsh[5],dsh[6],dsh[7]};
  int idx = bi*256 + tid;                            // [0, 90112)
  int hd = idx / 45056; int rem = idx - hd*45056;
  int b = rem / 88, j = rem - b*88;
  const float* W = hd ? Wsd : Wm;
  const float4* a4 = (const float4*)(zg3 + (size_t)b*184);
  const float4* w4 = (const float4*)(W + (size_t)j*184);
  float accv = hd ? Bsd[j] : Bm[j];
  #pragma unroll 2
  for (int i4=0;i4<46;i4++){
    float4 x = a4[i4]; float4 w = w4[i4];
    float4 sc = (i4&1)? s1 : s0; float4 sh = (i4&1)? t1 : t0;
    accv += w.x*(x.x*sc.x+sh.x) + w.y*(x.y*sc.y+sh.y)
          + w.z*(x.z*sc.z+sh.z) + w.w*(x.w*sc.w+sh.w);
  }
  if (hd) ods[(size_t)b*88+j] = sp_(accv);
  else    odm[(size_t)b*88+j] = accv;
}

// gru unit (256 thr): conflict-free transposed weights
__device__ __forceinline__ void dev_gru(
    float* smem, int idx,
    float* __restrict__ h, const float* __restrict__ x_t,
    const float* __restrict__ z, const float* __restrict__ Wih,
    const float* __restrict__ Whh, const float* __restrict__ bih,
    const float* __restrict__ bhh)
{
  int tid = threadIdx.x;
  float* WhT  = smem;           // 64*193 = 12352
  float* hs   = smem + 12352;   // 64*36  = 2304
  float* gins = smem + 14656;   // 8*36   = 288
  int a = idx >> 4, yb = idx & 15;
  int b0 = yb*32;
  int c = tid & 63, sq = tid >> 6;
  const float* Wg = Whh + (size_t)a*12288;
  for (int e = tid; e < 12288; e += 256) WhT[(e&63)*193 + (e>>6)] = Wg[e];
  const float* hp_g = h + (size_t)a*32768 + (size_t)b0*64;
  for (int e = tid; e < 2048; e += 256) hs[(e&63)*36 + (e>>6)] = hp_g[e];
  { int s = tid >> 3, k = tid & 7;
    float v = (k<4) ? x_t[(size_t)(b0+s)*92 + a*4 + k]
                    : z[(size_t)(b0+s)*92 + a*4 + (k-4)];
    gins[k*36 + s] = v; }
  float wi0[8], wi1[8], wi2[8];
  const float* Wig = Wih + (size_t)a*1536;
  #pragma unroll
  for (int k=0;k<8;k++){
    wi0[k] = Wig[c*8+k]; wi1[k] = Wig[(64+c)*8+k]; wi2[k] = Wig[(128+c)*8+k];
  }
  float bi0 = bih[a*192+c], bi1 = bih[a*192+64+c], bi2 = bih[a*192+128+c];
  float bh0 = bhh[a*192+c], bh1 = bhh[a*192+64+c], bh2 = bhh[a*192+128+c];
  __syncthreads();
  #pragma unroll
  for (int ps=0; ps<2; ps++){
    int s0 = ps*16 + sq*4;
    float q0[4], q1[4], q2[4];
    #pragma unroll
    for (int i=0;i<4;i++){ q0[i]=bh0; q1[i]=bh1; q2[i]=bh2; }
    for (int k=0;k<64;k++){
      float w0 = WhT[k*193 + c];
      float w1 = WhT[k*193 + 64 + c];
      float w2 = WhT[k*193 + 128 + c];
      float4 hv = *(const float4*)&hs[k*36 + s0];
      float hvv[4] = {hv.x,hv.y,hv.z,hv.w};
      #pragma unroll
      for (int i=0;i<4;i++){ q0[i]+=w0*hvv[i]; q1[i]+=w1*hvv[i]; q2[i]+=w2*hvv[i]; }
    }
    float g0[4], g1[4], g2[4];
    #pragma unroll
    for (int i=0;i<4;i++){ g0[i]=bi0; g1[i]=bi1; g2[i]=bi2; }
    #pragma unroll
    for (int k=0;k<8;k++){
      float4 gv = *(const float4*)&gins[k*36 + s0];
      float gvv[4] = {gv.x,gv.y,gv.z,gv.w};
      #pragma unroll
      for (int i=0;i<4;i++){ g0[i]+=wi0[k]*gvv[i]; g1[i]+=wi1[k]*gvv[i]; g2[i]+=wi2[k]*gvv[i]; }
    }
    float4 hp = *(const float4*)&hs[c*36 + s0];
    float hpv[4] = {hp.x,hp.y,hp.z,hp.w};
    #pragma unroll
    for (int i=0;i<4;i++){
      float rg = sig_(g0[i]+q0[i]);
      float zg = sig_(g1[i]+q1[i]);
      float ng = tanhf(g2[i] + rg*q2[i]);
      h[(size_t)a*32768 + (size_t)(b0+s0+i)*64 + c] = (1.f-zg)*ng + zg*hpv[i];
    }
  }
}

// ================= global kernels =================

__global__ __launch_bounds__(256) void k_stats1(
    const float* __restrict__ states,
    const float* __restrict__ W1b, const float* __restrict__ b1b,
    const float* __restrict__ W2b, const float* __restrict__ b2b,
    float* __restrict__ part)
{
  int g = blockIdx.y; int p = g/10; int t = g - p*10;
  const float* W1 = W1b + p*32; const float* b1 = b1b + p*8;
  const float* W2 = W2b + p*64; const float* b2 = b2b + p*8;
  int row = blockIdx.x*256 + threadIdx.x;            // [0, 11776)
  float4 x4 = *(const float4*)(states + (size_t)(t+p)*47104 + 4*(size_t)row);
  float h1[8], h2[8];
  #pragma unroll
  for (int j=0;j<8;j++)
    h1[j] = elu_(b1[j] + W1[j*4+0]*x4.x + W1[j*4+1]*x4.y + W1[j*4+2]*x4.z + W1[j*4+3]*x4.w);
  #pragma unroll
  for (int j=0;j<8;j++){
    float a = b2[j];
    #pragma unroll
    for (int k=0;k<8;k++) a += W2[j*8+k]*h1[k];
    h2[j] = elu_(a);
  }
  __shared__ float red[4][16];
  block_stats_(h2, part + ((size_t)g*46 + blockIdx.x)*16, red);
}

__global__ __launch_bounds__(256) void k_pre_edges(
    const float* __restrict__ states, const float* __restrict__ p1,
    const float* __restrict__ nW1, const float* __restrict__ nb1,
    const float* __restrict__ nW2, const float* __restrict__ nb2,
    const float* __restrict__ g1, const float* __restrict__ bt1,
    const float* __restrict__ eW1, const float* __restrict__ eb1,
    const float* __restrict__ eW2, const float* __restrict__ eb2,
    float* __restrict__ nodeacc, float* __restrict__ p2)
{
  __shared__ float smem[5274];
  int g = blockIdx.y, p = g/10, t = g - p*10;
  dev_edges(smem, blockIdx.x, g, p, t, states, 47104L, p1,
            nW1,nb1,nW2,nb2, g1,bt1, eW1,eb1,eW2,eb2, nodeacc, p2);
}

__global__ __launch_bounds__(256) void k_pre_node3(
    const float* __restrict__ nodeacc, const float* __restrict__ p2,
    const float* __restrict__ g2, const float* __restrict__ bt2,
    const float* __restrict__ W3, const float* __restrict__ b3,
    const float* __restrict__ W4, const float* __restrict__ b4,
    float* __restrict__ out, float* __restrict__ p3)
{
  int g = blockIdx.y, p = g/10;
  dev_node3(blockIdx.x, g, p, nodeacc, p2, g2, bt2, W3,b3,W4,b4, out, p3);
}

__global__ __launch_bounds__(256) void k_bnred(
    const float* __restrict__ part, int n, float invN,
    const float* __restrict__ gamb, const float* __restrict__ betb,
    float* __restrict__ scsh)
{
  int g = blockIdx.x; int p = g/10;
  int tid = threadIdx.x;
  __shared__ float tmp[256];
  const float* pp = part + (size_t)g*n*16;
  int c = tid & 15, i0 = tid >> 4;
  float s = 0.f;
  for (int i = i0; i < n; i += 16) s += pp[i*16 + c];
  tmp[i0*16 + c] = s;
  __syncthreads();
  if (tid < 16){
    float v = 0.f;
    #pragma unroll
    for (int i=0;i<16;i++) v += tmp[i*16 + tid];
    tmp[tid] = v;
  }
  __syncthreads();
  if (tid < 8){
    float m = tmp[tid]*invN;
    float var = tmp[8+tid]*invN - m*m;
    float rs = rsqrtf(var + 1e-5f);
    float sc = rs*gamb[p*8+tid];
    scsh[g*16 + tid] = sc;
    scsh[g*16 + 8 + tid] = betb[p*8+tid] - m*sc;
  }
}

// K1(t): [0,nh) heads(t), [nh,...) edges(t-1)
__global__ __launch_bounds__(256) void k_K1(
    int nh, int t,
    const float* __restrict__ gy, const float* __restrict__ gx,
    const float* __restrict__ scsh3, const float* __restrict__ h,
    const float* __restrict__ Wpm, const float* __restrict__ Wps,
    const float* __restrict__ Wem, const float* __restrict__ Wes,
    float* __restrict__ rawp,
    const float* __restrict__ zb, const float* __restrict__ zp1,
    const float* __restrict__ nW1, const float* __restrict__ nb1,
    const float* __restrict__ nW2, const float* __restrict__ nb2,
    const float* __restrict__ g1, const float* __restrict__ bt1,
    const float* __restrict__ eW1, const float* __restrict__ eb1,
    const float* __restrict__ eW2, const float* __restrict__ eb2,
    float* __restrict__ zna, float* __restrict__ zp2)
{
  __shared__ float smem[5274];
  if ((int)blockIdx.x < nh)
    dev_heads(smem, blockIdx.x, t, gy, gx, scsh3, h, Wpm,Wps,Wem,Wes, rawp);
  else
    dev_edges(smem, blockIdx.x - nh, 0, 0, 0, zb, 0L, zp1,
              nW1,nb1,nW2,nb2, g1,bt1, eW1,eb1,eW2,eb2, zna, zp2);
}

// K2(t): [0,nf) fused(t), [nf,...) node3(t-1)
__global__ __launch_bounds__(256) void k_K2(
    int nf,
    const float* __restrict__ rawp,
    const float* __restrict__ bpm, const float* __restrict__ bps,
    const float* __restrict__ bem, const float* __restrict__ bes,
    const float* __restrict__ eps_t, float* __restrict__ z,
    float* __restrict__ lklp,
    const float* __restrict__ W1, const float* __restrict__ b1,
    const float* __restrict__ W2, const float* __restrict__ b2,
    float* __restrict__ part,
    const float* __restrict__ zna, const float* __restrict__ zp2,
    const float* __restrict__ g2, const float* __restrict__ bt2,
    const float* __restrict__ W3, const float* __restrict__ b3,
    const float* __restrict__ W4, const float* __restrict__ b4,
    float* __restrict__ zg3, float* __restrict__ zp3)
{
  if ((int)blockIdx.x < nf)
    dev_fused(blockIdx.x, rawp, bpm,bps,bem,bes, eps_t, z, lklp, W1,b1,W2,b2, part);
  else
    dev_node3(blockIdx.x - nf, 0, 0, zna, zp2, g2, bt2, W3,b3,W4,b4, zg3, zp3);
}

// K3(t): [0,ngru) gru(t), [ngru,...) dec(t-1)
__global__ __launch_bounds__(256) void k_K3(
    int ngru,
    float* __restrict__ h, const float* __restrict__ x_t,
    const float* __restrict__ z, const float* __restrict__ Wih,
    const float* __restrict__ Whh, const float* __restrict__ bih,
    const float* __restrict__ bhh,
    const float* __restrict__ zg3, const float* __restrict__ p3,
    const float* __restrict__ gam, const float* __restrict__ bet,
    const float* __restrict__ Wm, const float* __restrict__ Bm,
    const float* __restrict__ Wsd, const float* __restrict__ Bsd,
    float* __restrict__ odm, float* __restrict__ ods)
{
  __shared__ float smem[14944];
  if ((int)blockIdx.x < ngru)
    dev_gru(smem, blockIdx.x, h, x_t, z, Wih, Whh, bih, bhh);
  else
    dev_dec(smem, blockIdx.x - ngru, zg3, p3, gam, bet, Wm,Bm,Wsd,Bsd, odm, ods);
}

__global__ __launch_bounds__(256) void k_final(const float* __restrict__ lklp,
                                               float* __restrict__ out){
  __shared__ float red[4];
  float s = 0.f;
  for (int i = threadIdx.x; i < 460; i += 256) s += lklp[i];
  s = wsum_(s);
  if ((threadIdx.x&63)==0) red[threadIdx.x>>6]=s;
  __syncthreads();
  if (threadIdx.x==0) out[0] = red[0]+red[1]+red[2]+red[3];
}

extern "C" void kernel_launch(void* const* d_in, const int* in_sizes, int n_in,
                              void* d_out, int out_size, void* d_ws, size_t ws_size,
                              hipStream_t stream)
{
  (void)in_sizes; (void)n_in; (void)out_size; (void)ws_size;
  const float* states=(const float*)d_in[0];
  const float* eps   =(const float*)d_in[1];
  const float *m1W1=(const float*)d_in[2],  *m1b1=(const float*)d_in[3],
              *m1W2=(const float*)d_in[4],  *m1b2=(const float*)d_in[5],
              *m1g =(const float*)d_in[6],  *m1bt=(const float*)d_in[7];
  const float *m2W1=(const float*)d_in[8],  *m2b1=(const float*)d_in[9],
              *m2W2=(const float*)d_in[10], *m2b2=(const float*)d_in[11],
              *m2g =(const float*)d_in[12], *m2bt=(const float*)d_in[13];
  const float *m3W1=(const float*)d_in[14], *m3b1=(const float*)d_in[15],
              *m3W2=(const float*)d_in[16], *m3b2=(const float*)d_in[17],
              *m3g =(const float*)d_in[18], *m3bt=(const float*)d_in[19];
  const float *emW=(const float*)d_in[20], *emB=(const float*)d_in[21];
  const float *esW=(const float*)d_in[22], *esB=(const float*)d_in[23];
  const float *pmW=(const float*)d_in[24], *pmB=(const float*)d_in[25];
  const float *psW=(const float*)d_in[26], *psB=(const float*)d_in[27];
  const float *dmW=(const float*)d_in[28], *dmB=(const float*)d_in[29];
  const float *dsW=(const float*)d_in[30], *dsB=(const float*)d_in[31];
  const float *gWih=(const float*)d_in[32], *gWhh=(const float*)d_in[33];
  const float *gbih=(const float*)d_in[34], *gbhh=(const float*)d_in[35];
  float* out = (float*)d_out;
  float* ws  = (float*)d_ws;

  // persistent (floats) — total 5,488,844 fl = 21.96 MB
  float* g3    = ws;                 // [20][11776][8] = 1,884,160 (pre-BN3)
  float* h     = ws + 1884160;       // 720,896
  float* zb    = ws + 2605056;       // 47,104
  float* lklp  = ws + 2652160;       // 460
  float* scsh3 = ws + 2652620;       // 320
  float* zp1   = ws + 2652940;       // 736
  float* zna   = ws + 2653676;       // 94,208
  float* zp2   = ws + 2747884;       // 8,192
  float* zg3   = ws + 2756076;       // 94,208
  float* zp3   = ws + 2850284;       // 736
  float* rawp  = ws + 2851020;       // [14][4][512][92] = 2,637,824
  // precompute aliases inside rawp (dead once scan starts)
  float* p1p = rawp;                 // [20][46][16]   = 14,720
  float* naP = rawp + 14720;         // [20][512][184] = 1,884,160
  float* p2p = rawp + 1898880;       // [20][512][16]  = 163,840
  float* p3p = rawp + 2062720;       // [20][46][16]   = 14,720

  hipMemsetAsync(h, 0, 720896*sizeof(float), stream);

  // ---- precompute gnn(y,p=0)/gnn(x,p=1), all t (g = p*10+t) ----
  k_stats1<<<dim3(46,20),256,0,stream>>>(states, m1W1, m1b1, m1W2, m1b2, p1p);
  k_pre_edges<<<dim3(512,20),256,0,stream>>>(states, p1p,
      m1W1, m1b1, m1W2, m1b2, m1g, m1bt,
      m2W1, m2b1, m2W2, m2b2, naP, p2p);
  k_pre_node3<<<dim3(46,20),256,0,stream>>>(naP, p2p, m2g, m2bt,
      m3W1, m3b1, m3W2, m3b2, g3, p3p);
  k_bnred<<<20,256,0,stream>>>(p3p, 46, 1.f/11776.f, m3g, m3bt, scsh3);

  // ---- software-pipelined scan: 11 iterations ----
  for (int t=0;t<=10;t++){
    int nh = (t<10)?448:0, ne = (t>0)?512:0;
    k_K1<<<nh+ne,256,0,stream>>>(nh, t,
        g3 + (size_t)(t<10?t:0)*94208, g3 + 942080 + (size_t)(t<10?t:0)*94208,
        scsh3, h, pmW, psW, emW, esW, rawp,
        zb, zp1,
        m1W1+64, m1b1+16, m1W2+128, m1b2+16, m1g+16, m1bt+16,
        m2W1+288, m2b1+16, m2W2+128, m2b2+16, zna, zp2);
    int nf = (t<10)?46:0, nn = (t>0)?46:0;
    k_K2<<<nf+nn,256,0,stream>>>(nf,
        rawp, pmB, psB, emB, esB,
        eps + (size_t)(t<10?t:0)*47104, zb, lklp + (t<10?t:0)*46,
        m1W1+64, m1b1+16, m1W2+128, m1b2+16, zp1,
        zna, zp2, m2g+16, m2bt+16,
        m3W1+160, m3b1+16, m3W2+128, m3b2+16, zg3, zp3);
    int ng = (t<10)?352:0, nd = (t>0)?352:0;
    float* odm = (t>0) ? out + (size_t)(t-1)*45056 : out;
    float* ods = (t>0) ? out + 450560 + (size_t)(t-1)*45056 : out;
    k_K3<<<ng+nd,256,0,stream>>>(ng,
        h, states + (size_t)(t<10?t+1:1)*47104, zb, gWih, gWhh, gbih, gbhh,
        zg3, zp3, m3g+16, m3bt+16, dmW, dmB, dsW, dsB, odm, ods);
  }
  k_final<<<1,256,0,stream>>>(lklp, out + 901120);
}